// Round 5
// baseline (30141.910 us; speedup 1.0000x reference)
//
#include <hip/hip_runtime.h>

// ---------------------------------------------------------------------------
// 2-layer LSTM encoder, B=128 T=512 E=256 H=1024 (round 5).
// Persistent kernel: 256 blocks x 1024 threads (16 waves, 4/SIMD).
// Layer-specialized waves: waves 0-7 -> L0 GEMM/cell, waves 8-15 -> L1.
// Per phase p:  L0 (t=p): z0=[x_p;h0(p-1)]@W0 -> h0(p)
//               L1 (t=p-1): z1=[h0(p-1);h1(p-2)]@W1 -> h1(p-1)
// Split-bf16 x3 MFMA (verified r1-r4). W-hi LDS-resident; W-lo streamed
// (L2/HBM). A-frags direct global->reg from per-XCD replica. Flag barriers.
// NEW: 2x occupancy (4 waves/SIMD), dist overlapped with L0 x-part,
// per-layer wave specialization halves each wave's dependency chain.
// ---------------------------------------------------------------------------

namespace {
constexpr int NBLK = 256, THREADS = 1024;
constexpr int KT0B = 40;           // L0 k-tiles of 32 (K=1280)
constexpr int KT1B = 64;           // L1 k-tiles of 32 (K=2048)
constexpr int NPH = 513;
constexpr int HP = 128 * 1024;     // u16 elems per h plane
constexpr int SPIN_CAP = 2000000;
// flag slots (u32 index into ctr[1024])
constexpr int F_CREG = 0;          // 8 x 16 (boot atomics)
constexpr int F_BOOT = 128;
constexpr int F_ARR  = 256;        // 256 contiguous
constexpr int F_GO   = 520;
constexpr int F_XARR = 576;        // 8 x 32
constexpr int F_XGO  = 832;        // 8 x 16
}

typedef __bf16 bf16x8 __attribute__((ext_vector_type(8)));
typedef float f32x4 __attribute__((ext_vector_type(4)));
typedef unsigned short u16x4 __attribute__((ext_vector_type(4)));

__device__ __forceinline__ unsigned short f2bf(float f) {
  unsigned u = __float_as_uint(f);
  u += 0x7fffu + ((u >> 16) & 1u);
  return (unsigned short)(u >> 16);
}
__device__ __forceinline__ float bf2f(unsigned short h) {
  return __uint_as_float(((unsigned)h) << 16);
}
__device__ __forceinline__ float sigm(float x) { return 1.0f / (1.0f + __expf(-x)); }
__device__ __forceinline__ float tanh_f(float x) {
  float e = __expf(-2.0f * fabsf(x));
  float r = (1.0f - e) / (1.0f + e);
  return x >= 0.0f ? r : -r;
}

// ---- LLC-coherent ops (bypass L1+L2) --------------------------------------
__device__ __forceinline__ int load_i32_llc(const int* p) {
  int v;
  asm volatile("global_load_dword %0, %1, off sc0 sc1\n\ts_waitcnt vmcnt(0)"
               : "=v"(v) : "v"(p) : "memory");
  return v;
}
__device__ __forceinline__ uint4 llc_load_issue(const unsigned* p) {
  uint4 v;
  asm volatile("global_load_dwordx4 %0, %1, off sc0 sc1" : "=v"(v) : "v"(p));
  return v;
}
__device__ __forceinline__ void vm_wait0() {
  asm volatile("s_waitcnt vmcnt(0)" ::: "memory");
  __builtin_amdgcn_sched_barrier(0);
}
__device__ __forceinline__ void store_u32_llc(unsigned* p, unsigned v) {
  asm volatile("global_store_dword %0, %1, off sc0 sc1" :: "v"(p), "v"(v) : "memory");
}
__device__ __forceinline__ void store_u16_llc(unsigned short* p, unsigned short v) {
  asm volatile("global_store_short %0, %1, off sc0 sc1" :: "v"(p), "v"(v) : "memory");
}
__device__ __forceinline__ void inv_l1() {
  asm volatile("buffer_inv" ::: "memory");
}
__device__ __forceinline__ int xcc_id() {
  int x;
  asm("s_getreg_b32 %0, hwreg(HW_REG_XCC_ID)" : "=s"(x));
  return x & 7;
}
__device__ __forceinline__ int spin_ge(int* p, int target) {
  for (int it = 0; it < SPIN_CAP; ++it) {
    if (load_i32_llc(p) >= target) return 1;
    __builtin_amdgcn_s_sleep(1);
  }
  return 0;
}

__device__ __forceinline__ bf16x8 frag2(const unsigned short* pk) {
  u16x4 a = *(const u16x4*)pk;
  u16x4 b = *(const u16x4*)(pk + 16);
  return __builtin_bit_cast(bf16x8,
      __builtin_shufflevector(a, b, 0, 1, 2, 3, 4, 5, 6, 7));
}
__device__ __forceinline__ bf16x8 asbf(uint4 v) {
  return __builtin_bit_cast(bf16x8, v);
}

#define MFMA3(acc, ah, al, bh, bl)                                            \
  acc = __builtin_amdgcn_mfma_f32_16x16x32_bf16(ah, bh, acc, 0, 0, 0);        \
  acc = __builtin_amdgcn_mfma_f32_16x16x32_bf16(ah, bl, acc, 0, 0, 0);        \
  acc = __builtin_amdgcn_mfma_f32_16x16x32_bf16(al, bh, acc, 0, 0, 0);

// ======================= prep kernels =====================================

__global__ void prep_sort(const int* __restrict__ lens, int* __restrict__ perm,
                          int* __restrict__ lenS, int* __restrict__ ncnt) {
  __shared__ int k_[128], p_[128];
  const int tid = threadIdx.x;
  if (tid < 128) { k_[tid] = (lens[tid] << 8) | (127 - tid); p_[tid] = tid; }
  __syncthreads();
  for (int ph = 0; ph < 128; ++ph) {
    if (tid < 64) {
      int a = 2 * tid + (ph & 1), b = a + 1;
      if (b < 128 && k_[a] < k_[b]) {
        int tk = k_[a]; k_[a] = k_[b]; k_[b] = tk;
        int tp = p_[a]; p_[a] = p_[b]; p_[b] = tp;
      }
    }
    __syncthreads();
  }
  if (tid < 128) { perm[tid] = p_[tid]; lenS[tid] = k_[tid] >> 8; }
  if (tid < 512) {
    int c = 0;
    for (int i = 0; i < 128; ++i) c += ((k_[i] >> 8) > tid) ? 1 : 0;
    ncnt[tid] = c;
  }
}

__global__ void prep_emb(const float* __restrict__ emb,
                         unsigned short* __restrict__ ehi,
                         unsigned short* __restrict__ elo) {
  int i = blockIdx.x * 256 + threadIdx.x;   // 32768
  float f = emb[i];
  unsigned short h = f2bf(f);
  ehi[i] = h;
  elo[i] = f2bf(f - bf2f(h));
}

// W[k][4096] -> per-block frag slabs: e = (blk*KT + kt)*64 + lane.
// lane: cf = lane&15 = u_local*4 + g ; col = g*1024 + blk*4 + u_local
// elem j: k = kt*32 + ((lane>>4)&3)*4 + (j&3) + 16*(j>>2)
__global__ void prep_wslab(const float* __restrict__ W, uint4* __restrict__ Whi,
                           uint4* __restrict__ Wlo, int KT) {
  int e = blockIdx.x * 256 + threadIdx.x;
  int lane = e & 63;
  int kt = (e >> 6) % KT;
  int blk = e / (64 * KT);
  int cf = lane & 15;
  int g = cf & 3, ul = cf >> 2;
  int col = g * 1024 + blk * 4 + ul;
  int kbase = kt * 32 + ((lane >> 4) & 3) * 4;
  unsigned hi[8], lo[8];
#pragma unroll
  for (int j = 0; j < 8; ++j) {
    int k = kbase + (j & 3) + 16 * (j >> 2);
    float f = W[(size_t)k * 4096 + col];
    unsigned short h = f2bf(f);
    hi[j] = h;
    lo[j] = f2bf(f - bf2f(h));
  }
  uint4 vh, vl;
  vh.x = hi[0] | (hi[1] << 16); vh.y = hi[2] | (hi[3] << 16);
  vh.z = hi[4] | (hi[5] << 16); vh.w = hi[6] | (hi[7] << 16);
  vl.x = lo[0] | (lo[1] << 16); vl.y = lo[2] | (lo[3] << 16);
  vl.z = lo[4] | (lo[5] << 16); vl.w = lo[6] | (lo[7] << 16);
  Whi[e] = vh;
  Wlo[e] = vl;
}

// ======================= persistent kernel =================================

__global__ __launch_bounds__(THREADS, 1) void lstm_persist(
    const int* __restrict__ ib,
    const float* __restrict__ bias0, const float* __restrict__ bias1,
    const uint4* __restrict__ Whi0g, const uint4* __restrict__ Wlo0g,
    const uint4* __restrict__ Whi1g, const uint4* __restrict__ Wlo1g,
    const unsigned short* __restrict__ embHi, const unsigned short* __restrict__ embLo,
    const int* __restrict__ perm, const int* __restrict__ lenS,
    const int* __restrict__ ncnt,
    unsigned short* hg0hi, unsigned short* hg0lo,   // [3][128][1024]
    unsigned short* hg1hi, unsigned short* hg1lo,
    unsigned short* rep,                            // [8][4][128][1024]
    int* ctr, float* __restrict__ out) {
  const int bid = blockIdx.x;
  const int tid = threadIdx.x;
  const int w = tid >> 6;                 // wave 0..15
  const bool isL0 = (w < 8);
  const int wl = isL0 ? w : w - 8;        // layer-local wave 0..7
  const int lane = tid & 63;
  const int lr = lane & 15;
  const int lg4 = ((lane >> 4) & 3) * 4;
  const int arow = wl * 16 + lr;          // GEMM A row for this lane
  const int crow = (tid & 511) >> 2;      // cell row 0..127 (per layer half)
  const int cu = tid & 3;                 // cell unit 0..3
  const int ug = bid * 4 + cu;            // global unit
  const int permA = perm[arow];
  const int cperm = perm[crow];
  const int clen = lenS[crow];

  __shared__ uint4 Wh0[KT0B * 64];        // 40 KB
  __shared__ uint4 Wh1[KT1B * 64];        // 64 KB
  __shared__ float zb[2][128][17];        // 17 KB
  __shared__ int s_x, s_rk, s_R, s_ok;

  // ---- one-time: W-hi slabs -> LDS ----
  {
    const uint4* s0 = Whi0g + (size_t)bid * (KT0B * 64);
    for (int i = tid; i < KT0B * 64; i += THREADS) Wh0[i] = s0[i];
    const uint4* s1 = Whi1g + (size_t)bid * (KT1B * 64);
    for (int i = tid; i < KT1B * 64; i += THREADS) Wh1[i] = s1[i];
  }

  // bias for this thread's layer role
  float bz[4];
#pragma unroll
  for (int g = 0; g < 4; ++g)
    bz[g] = (isL0 ? bias0 : bias1)[g * 1024 + ug];
  float cr = 0.0f;                        // cell state in register

  // ---- bootstrap: XCD registration + first global sync (atomics, once) ----
  if (tid == 0) {
    s_ok = 1;
    int x = xcc_id();
    s_x = x;
    s_rk = atomicAdd(&ctr[F_CREG + x * 16], 1);
    vm_wait0();
    atomicAdd(&ctr[F_BOOT], 1);
    if (!spin_ge(&ctr[F_BOOT], NBLK)) s_ok = 0;
    int Rv = 1;
    for (int i = 0; i < 8; ++i) {
      int r = load_i32_llc(&ctr[F_CREG + i * 16]);
      if (i == s_x) Rv = r;
    }
    s_R = Rv;
  }
  __syncthreads();
  const int xcd = s_x, rk = s_rk, R = s_R;
  if (!s_ok) return;

  unsigned short* repB = rep + (size_t)xcd * 4 * HP;
  const unsigned short* rh0 = repB;               // h0 hi | lo at +HP
  const unsigned short* rh1 = repB + 2 * HP;      // h1 hi | lo at +HP

  // distribution role (L1 waves only): plane pr, 16B chunk ch
  const int tid2 = tid - 512;
  const int pr = (tid2 >= 0) ? (tid2 >> 7) : 0;   // 0..3: h0hi,h0lo,h1hi,h1lo
  const int ch = (tid2 & 127) * 8;                // u16 offset (16B chunk)
  const unsigned short* spBase =
      (pr == 0) ? hg0hi : (pr == 1) ? hg0lo : (pr == 2) ? hg1hi : hg1lo;
  unsigned short* dp = repB + pr * HP;
  const uint4* wl0g = Wlo0g + (size_t)bid * (KT0B * 64) + lane;
  const uint4* wl1g = Wlo1g + (size_t)bid * (KT1B * 64) + lane;

  for (int p = 0; p < NPH; ++p) {
    const int nact0 = (p < 512) ? ncnt[p] : 0;
    const int nact1 = (p >= 1) ? ncnt[p - 1] : 0;
    const bool doL0 = isL0 && (p < 512) && (wl * 16 < nact0);
    const bool doL1 = !isL0 && (p >= 1) && (wl * 16 < nact1);

    f32x4 acc = (f32x4){0.f, 0.f, 0.f, 0.f};

    if (!isL0) {
      // ---- L1 waves: distribute h0(p-1), h1(p-2) into XCD replica ----
      const int ncopy = ncnt[p == 0 ? 0 : p - 1];
      const int par = (pr < 2) ? (p + 2) % 3 : (p + 1) % 3;
      const unsigned short* sp = spBase + (size_t)par * HP;
      for (int rb = rk; rb < ncopy; rb += 4 * R) {
        const int r1 = rb + R, r2 = rb + 2 * R, r3 = rb + 3 * R;
        uint4 v0, v1, v2, v3;
        v0 = llc_load_issue((const unsigned*)(sp + rb * 1024 + ch));
        if (r1 < ncopy) v1 = llc_load_issue((const unsigned*)(sp + r1 * 1024 + ch));
        if (r2 < ncopy) v2 = llc_load_issue((const unsigned*)(sp + r2 * 1024 + ch));
        if (r3 < ncopy) v3 = llc_load_issue((const unsigned*)(sp + r3 * 1024 + ch));
        vm_wait0();
        *(uint4*)(dp + rb * 1024 + ch) = v0;
        if (r1 < ncopy) *(uint4*)(dp + r1 * 1024 + ch) = v1;
        if (r2 < ncopy) *(uint4*)(dp + r2 * 1024 + ch) = v2;
        if (r3 < ncopy) *(uint4*)(dp + r3 * 1024 + ch) = v3;
      }
    } else if (doL0) {
      // ---- L0 waves: x-part (no h dependency) overlapped with dist ----
      const int tok = ib[(size_t)permA * 512 + p];
      const unsigned short* eh = embHi + tok * 256;
      const unsigned short* el = embLo + tok * 256;
#pragma unroll 4
      for (int kt = 0; kt < 8; ++kt) {
        const int kb = kt * 32 + lg4;
        const bf16x8 ah = frag2(eh + kb), al = frag2(el + kb);
        const bf16x8 bh = asbf(Wh0[kt * 64 + lane]);
        const bf16x8 bl = asbf(wl0g[kt * 64]);
        MFMA3(acc, ah, al, bh, bl)
      }
    }
    __syncthreads();                       // drains dist vmem
    // ---- XCD barrier (flag-based) ----
    if (tid == 0) store_u32_llc((unsigned*)&ctr[F_XARR + xcd * 32 + rk], p + 1);
    if (rk == 0 && tid < 32 && tid < R) {
      if (!spin_ge(&ctr[F_XARR + xcd * 32 + tid], p + 1)) s_ok = 0;
    }
    __syncthreads();
    if (rk == 0 && tid == 0) store_u32_llc((unsigned*)&ctr[F_XGO + xcd * 16], p + 1);
    if (tid == 0) {
      if (!spin_ge(&ctr[F_XGO + xcd * 16], p + 1)) s_ok = 0;
    }
    __syncthreads();
    if (!s_ok) break;
    inv_l1();                              // fresh L1 view of replica

    // ---- h-part GEMMs (layer-specialized waves) ----
    if (doL0) {
      const unsigned short* hh = rh0 + arow * 1024;
      const unsigned short* hl = rh0 + HP + arow * 1024;
#pragma unroll 4
      for (int q = 0; q < 32; ++q) {
        const int kb = q * 32 + lg4;
        const bf16x8 ah = frag2(hh + kb), al = frag2(hl + kb);
        const bf16x8 bh = asbf(Wh0[(q + 8) * 64 + lane]);
        const bf16x8 bl = asbf(wl0g[(q + 8) * 64]);
        MFMA3(acc, ah, al, bh, bl)
      }
    }
    if (doL1) {
      {
        const unsigned short* hh = rh0 + arow * 1024;
        const unsigned short* hl = rh0 + HP + arow * 1024;
#pragma unroll 4
        for (int q = 0; q < 32; ++q) {
          const int kb = q * 32 + lg4;
          const bf16x8 ah = frag2(hh + kb), al = frag2(hl + kb);
          const bf16x8 bh = asbf(Wh1[q * 64 + lane]);
          const bf16x8 bl = asbf(wl1g[q * 64]);
          MFMA3(acc, ah, al, bh, bl)
        }
      }
      {
        const unsigned short* hh = rh1 + arow * 1024;
        const unsigned short* hl = rh1 + HP + arow * 1024;
#pragma unroll 4
        for (int q = 0; q < 32; ++q) {
          const int kb = q * 32 + lg4;
          const bf16x8 ah = frag2(hh + kb), al = frag2(hl + kb);
          const bf16x8 bh = asbf(Wh1[(q + 32) * 64 + lane]);
          const bf16x8 bl = asbf(wl1g[(q + 32) * 64]);
          MFMA3(acc, ah, al, bh, bl)
        }
      }
    }

    // ---- z exchange (C/D: row = 4*(l>>4)+reg, col = l&15) ----
    if (doL0) {
#pragma unroll
      for (int rr = 0; rr < 4; ++rr) zb[0][wl * 16 + lg4 + rr][lr] = acc[rr];
    }
    if (doL1) {
#pragma unroll
      for (int rr = 0; rr < 4; ++rr) zb[1][wl * 16 + lg4 + rr][lr] = acc[rr];
    }
    __syncthreads();

    // ---- fused cells (layer halves; c in registers) ----
    if (isL0) {
      if (p < 512 && p < clen) {          // L0, t = p
        const float zi = zb[0][crow][cu * 4 + 0] + bz[0];
        const float zj = zb[0][crow][cu * 4 + 1] + bz[1];
        const float zf = zb[0][crow][cu * 4 + 2] + bz[2];
        const float zo = zb[0][crow][cu * 4 + 3] + bz[3];
        const float nc = cr * sigm(zf + 1.0f) + sigm(zi) * tanh_f(zj);
        const float nh = tanh_f(nc) * sigm(zo);
        cr = nc;
        const unsigned short hh = f2bf(nh);
        const unsigned short hl = f2bf(nh - bf2f(hh));
        const size_t idx = (size_t)(p % 3) * HP + crow * 1024 + ug;
        store_u16_llc(&hg0hi[idx], hh);
        store_u16_llc(&hg0lo[idx], hl);
      }
    } else {
      if (p >= 1 && (p - 1) < clen) {     // L1, t = p-1
        const float zi = zb[1][crow][cu * 4 + 0] + bz[0];
        const float zj = zb[1][crow][cu * 4 + 1] + bz[1];
        const float zf = zb[1][crow][cu * 4 + 2] + bz[2];
        const float zo = zb[1][crow][cu * 4 + 3] + bz[3];
        const float nc = cr * sigm(zf + 1.0f) + sigm(zi) * tanh_f(zj);
        const float nh = tanh_f(nc) * sigm(zo);
        cr = nc;
        const unsigned short hh = f2bf(nh);
        const unsigned short hl = f2bf(nh - bf2f(hh));
        const size_t idx = (size_t)((p + 2) % 3) * HP + crow * 1024 + ug;
        store_u16_llc(&hg1hi[idx], hh);
        store_u16_llc(&hg1lo[idx], hl);
        if (p - 1 == clen - 1) out[(size_t)cperm * 1024 + ug] = nh;
      }
    }

    // ---- global barrier (flag-based) ----
    __syncthreads();                      // drains all waves' vmem
    if (tid == 0) store_u32_llc((unsigned*)&ctr[F_ARR + bid], p + 1);
    if (bid == 0) {
      if (tid < 256) {
        if (!spin_ge(&ctr[F_ARR + tid], p + 1)) s_ok = 0;
      }
      __syncthreads();
      if (tid == 0) store_u32_llc((unsigned*)&ctr[F_GO], p + 1);
    }
    if (tid == 0) {
      if (!spin_ge(&ctr[F_GO], p + 1)) s_ok = 0;
    }
    __syncthreads();
    if (!s_ok) break;
  }
}

// ======================= host launch =======================================

extern "C" void kernel_launch(void* const* d_in, const int* in_sizes, int n_in,
                              void* d_out, int out_size, void* d_ws, size_t ws_size,
                              hipStream_t stream) {
  const int*   ib   = (const int*)d_in[0];
  const int*   lens = (const int*)d_in[1];
  const float* emb  = (const float*)d_in[2];
  const float* W0   = (const float*)d_in[3];
  const float* b0   = (const float*)d_in[4];
  const float* W1   = (const float*)d_in[5];
  const float* b1   = (const float*)d_in[6];
  (void)in_sizes; (void)n_in; (void)out_size; (void)ws_size;

  char* ws = (char*)d_ws;
  size_t off = 0;
  auto alloc = [&](size_t bytes) { char* q = ws + off; off += (bytes + 255) & ~(size_t)255; return q; };

  int*            ctr   = (int*)alloc(4096);
  unsigned short* hg0hi = (unsigned short*)alloc((size_t)3 * HP * 2);
  unsigned short* hg0lo = (unsigned short*)alloc((size_t)3 * HP * 2);
  unsigned short* hg1hi = (unsigned short*)alloc((size_t)3 * HP * 2);
  unsigned short* hg1lo = (unsigned short*)alloc((size_t)3 * HP * 2);
  const size_t zero_bytes = off;          // ctr + h planes
  unsigned short* embHi = (unsigned short*)alloc(128 * 256 * 2);
  unsigned short* embLo = (unsigned short*)alloc(128 * 256 * 2);
  int*            perm  = (int*)alloc(4096);   // perm[128], lenS[128], ncnt[512]
  int*            lenS  = perm + 128;
  int*            ncnt  = perm + 256;
  unsigned short* rep   = (unsigned short*)alloc((size_t)8 * 4 * HP * 2);
  uint4*          Whi0  = (uint4*)alloc((size_t)NBLK * KT0B * 64 * 16);
  uint4*          Wlo0  = (uint4*)alloc((size_t)NBLK * KT0B * 64 * 16);
  uint4*          Whi1  = (uint4*)alloc((size_t)NBLK * KT1B * 64 * 16);
  uint4*          Wlo1  = (uint4*)alloc((size_t)NBLK * KT1B * 64 * 16);

  hipMemsetAsync(d_ws, 0, zero_bytes, stream);
  prep_sort<<<1, 512, 0, stream>>>(lens, perm, lenS, ncnt);
  prep_emb<<<128, 256, 0, stream>>>(emb, embHi, embLo);
  prep_wslab<<<(NBLK * KT0B * 64) / 256, 256, 0, stream>>>(W0, Whi0, Wlo0, KT0B);
  prep_wslab<<<(NBLK * KT1B * 64) / 256, 256, 0, stream>>>(W1, Whi1, Wlo1, KT1B);
  lstm_persist<<<NBLK, THREADS, 0, stream>>>(
      ib, b0, b1, Whi0, Wlo0, Whi1, Wlo1, embHi, embLo,
      perm, lenS, ncnt, hg0hi, hg0lo, hg1hi, hg1lo, rep, ctr, (float*)d_out);
}

// Round 6
// 25131.830 us; speedup vs baseline: 1.1994x; 1.1994x over previous
//
#include <hip/hip_runtime.h>

// ---------------------------------------------------------------------------
// 2-layer LSTM encoder, B=128 T=512 E=256 H=1024 (round 6).
// Persistent kernel: 256 blocks x 512 threads (8 waves, fused dual-layer).
// Per phase p: L0 (t=p): z0=[x_p;h0(p-1)]@W0 -> h0(p)
//             L1 (t=p-1): z1=[h0(p-1);h1(p-2)]@W1 -> h1(p-1)
// Split-bf16 x3 MFMA (verified r1-r5). W-hi LDS-resident.
// NEW r6: (1) W-lo streamed with NT loads (no L2 pollution -> replica stays
// L2-resident, no writeback thrash); (2) register-pipelined kt loops
// (PF=4 double-buffered groups, static unroll); (3) h/emb stored in
// MFMA-fragment-interleaved order -> A frag = ONE 16B load; dist is a pure
// linear copy; (4) 1-round XCD barrier.
// ---------------------------------------------------------------------------

namespace {
constexpr int NBLK = 256, THREADS = 512;
constexpr int KT0B = 40;           // L0 k-tiles of 32 (K=1280)
constexpr int KT1B = 64;           // L1 k-tiles of 32 (K=2048)
constexpr int NPH = 513;
constexpr int HP = 128 * 1024;     // u16 elems per h plane
constexpr int SPIN_CAP = 2000000;
// flag slots (u32 index into ctr[1024], all zeroed per launch)
constexpr int F_CREG = 0;          // 8 x 16 (boot atomics)
constexpr int F_BOOT = 128;
constexpr int F_ARR  = 256;        // 256 contiguous
constexpr int F_GO   = 520;
constexpr int F_XARR = 576;        // 8 x 32
}

typedef __bf16 bf16x8 __attribute__((ext_vector_type(8)));
typedef float f32x4 __attribute__((ext_vector_type(4)));
typedef unsigned u32x4 __attribute__((ext_vector_type(4)));

__host__ __device__ __forceinline__ int fswz(int kk) {   // frag order within 32
  return ((kk & 15) >> 2) * 8 + (kk >> 4) * 4 + (kk & 3);
}

__device__ __forceinline__ unsigned short f2bf(float f) {
  unsigned u = __float_as_uint(f);
  u += 0x7fffu + ((u >> 16) & 1u);
  return (unsigned short)(u >> 16);
}
__device__ __forceinline__ float bf2f(unsigned short h) {
  return __uint_as_float(((unsigned)h) << 16);
}
__device__ __forceinline__ float sigm(float x) { return 1.0f / (1.0f + __expf(-x)); }
__device__ __forceinline__ float tanh_f(float x) {
  float e = __expf(-2.0f * fabsf(x));
  float r = (1.0f - e) / (1.0f + e);
  return x >= 0.0f ? r : -r;
}

// ---- LLC-coherent ops (bypass L1+L2) --------------------------------------
__device__ __forceinline__ int load_i32_llc(const int* p) {
  int v;
  asm volatile("global_load_dword %0, %1, off sc0 sc1\n\ts_waitcnt vmcnt(0)"
               : "=v"(v) : "v"(p) : "memory");
  return v;
}
__device__ __forceinline__ uint4 llc_load_issue(const unsigned* p) {
  uint4 v;
  asm volatile("global_load_dwordx4 %0, %1, off sc0 sc1" : "=v"(v) : "v"(p));
  return v;
}
__device__ __forceinline__ void vm_wait0() {
  asm volatile("s_waitcnt vmcnt(0)" ::: "memory");
  __builtin_amdgcn_sched_barrier(0);
}
__device__ __forceinline__ void store_u32_llc(unsigned* p, unsigned v) {
  asm volatile("global_store_dword %0, %1, off sc0 sc1" :: "v"(p), "v"(v) : "memory");
}
__device__ __forceinline__ void store_u16_llc(unsigned short* p, unsigned short v) {
  asm volatile("global_store_short %0, %1, off sc0 sc1" :: "v"(p), "v"(v) : "memory");
}
__device__ __forceinline__ void inv_l1() {
  asm volatile("buffer_inv" ::: "memory");
}
__device__ __forceinline__ int xcc_id() {
  int x;
  asm("s_getreg_b32 %0, hwreg(HW_REG_XCC_ID)" : "=s"(x));
  return x & 7;
}
__device__ __forceinline__ int spin_ge(int* p, int target) {
  for (int it = 0; it < SPIN_CAP; ++it) {
    if (load_i32_llc(p) >= target) return 1;
    __builtin_amdgcn_s_sleep(1);
  }
  return 0;
}
__device__ __forceinline__ bf16x8 asbf(u32x4 v) { return __builtin_bit_cast(bf16x8, v); }
__device__ __forceinline__ bf16x8 asbf4(uint4 v) { return __builtin_bit_cast(bf16x8, v); }

#define MFMA3(acc, ah, al, bh, bl)                                            \
  acc = __builtin_amdgcn_mfma_f32_16x16x32_bf16(ah, bh, acc, 0, 0, 0);        \
  acc = __builtin_amdgcn_mfma_f32_16x16x32_bf16(ah, bl, acc, 0, 0, 0);        \
  acc = __builtin_amdgcn_mfma_f32_16x16x32_bf16(al, bh, acc, 0, 0, 0);

// ======================= prep kernels =====================================

__global__ void prep_sort(const int* __restrict__ lens, int* __restrict__ perm,
                          int* __restrict__ lenS, int* __restrict__ ncnt) {
  __shared__ int k_[128], p_[128];
  const int tid = threadIdx.x;
  if (tid < 128) { k_[tid] = (lens[tid] << 8) | (127 - tid); p_[tid] = tid; }
  __syncthreads();
  for (int ph = 0; ph < 128; ++ph) {
    if (tid < 64) {
      int a = 2 * tid + (ph & 1), b = a + 1;
      if (b < 128 && k_[a] < k_[b]) {
        int tk = k_[a]; k_[a] = k_[b]; k_[b] = tk;
        int tp = p_[a]; p_[a] = p_[b]; p_[b] = tp;
      }
    }
    __syncthreads();
  }
  if (tid < 128) { perm[tid] = p_[tid]; lenS[tid] = k_[tid] >> 8; }
  if (tid < 512) {
    int c = 0;
    for (int i = 0; i < 128; ++i) c += ((k_[i] >> 8) > tid) ? 1 : 0;
    ncnt[tid] = c;
  }
}

// emb planes in fragment-interleaved order
__global__ void prep_emb(const float* __restrict__ emb,
                         unsigned short* __restrict__ ehi,
                         unsigned short* __restrict__ elo) {
  int i = blockIdx.x * 256 + threadIdx.x;   // 32768
  int row = i >> 8, e = i & 255;
  int pos = row * 256 + (e >> 5) * 32 + fswz(e & 31);
  float f = emb[i];
  unsigned short h = f2bf(f);
  ehi[pos] = h;
  elo[pos] = f2bf(f - bf2f(h));
}

// W[k][4096] -> per-block frag slabs: e = (blk*KT + kt)*64 + lane.
// lane: cf = lane&15 = u_local*4 + g ; col = g*1024 + blk*4 + u_local
// elem j: k = kt*32 + ((lane>>4)&3)*4 + (j&3) + 16*(j>>2)
__global__ void prep_wslab(const float* __restrict__ W, uint4* __restrict__ Whi,
                           uint4* __restrict__ Wlo, int KT) {
  int e = blockIdx.x * 256 + threadIdx.x;
  int lane = e & 63;
  int kt = (e >> 6) % KT;
  int blk = e / (64 * KT);
  int cf = lane & 15;
  int g = cf & 3, ul = cf >> 2;
  int col = g * 1024 + blk * 4 + ul;
  int kbase = kt * 32 + ((lane >> 4) & 3) * 4;
  unsigned hi[8], lo[8];
#pragma unroll
  for (int j = 0; j < 8; ++j) {
    int k = kbase + (j & 3) + 16 * (j >> 2);
    float f = W[(size_t)k * 4096 + col];
    unsigned short h = f2bf(f);
    hi[j] = h;
    lo[j] = f2bf(f - bf2f(h));
  }
  uint4 vh, vl;
  vh.x = hi[0] | (hi[1] << 16); vh.y = hi[2] | (hi[3] << 16);
  vh.z = hi[4] | (hi[5] << 16); vh.w = hi[6] | (hi[7] << 16);
  vl.x = lo[0] | (lo[1] << 16); vl.y = lo[2] | (lo[3] << 16);
  vl.z = lo[4] | (lo[5] << 16); vl.w = lo[6] | (lo[7] << 16);
  Whi[e] = vh;
  Wlo[e] = vl;
}

// ======================= persistent kernel =================================

__global__ __launch_bounds__(THREADS, 2) void lstm_persist(
    const int* __restrict__ ib,
    const float* __restrict__ bias0, const float* __restrict__ bias1,
    const uint4* __restrict__ Whi0g, const uint4* __restrict__ Wlo0g,
    const uint4* __restrict__ Whi1g, const uint4* __restrict__ Wlo1g,
    const unsigned short* __restrict__ embHi, const unsigned short* __restrict__ embLo,
    const int* __restrict__ perm, const int* __restrict__ lenS,
    const int* __restrict__ ncnt,
    unsigned short* hg0hi, unsigned short* hg0lo,   // [3][128][1024] frag-order
    unsigned short* hg1hi, unsigned short* hg1lo,
    unsigned short* rep,                            // [8][4][128][1024]
    int* ctr, float* __restrict__ out) {
  const int bid = blockIdx.x;
  const int tid = threadIdx.x;
  const int w = tid >> 6;                 // wave 0..7 -> rows w*16..+15
  const int lane = tid & 63;
  const int lr = lane & 15;
  const int lg4 = ((lane >> 4) & 3) * 4;
  const int slotE = ((lane >> 4) & 3) * 8;  // frag u16 offset within 32-group
  const int arow = w * 16 + lr;           // GEMM A row for this lane
  const int srow = tid >> 2;              // cell row 0..127
  const int cu = tid & 3;                 // cell unit 0..3
  const int ug = bid * 4 + cu;            // global unit
  const int fpos = (ug >> 5) * 32 + fswz(ug & 31);  // frag pos of unit in row
  const int permA = perm[arow];
  const int cperm = perm[srow];
  const int clen = lenS[srow];

  __shared__ uint4 Wh0[KT0B * 64];        // 40 KB
  __shared__ uint4 Wh1[KT1B * 64];        // 64 KB
  __shared__ float zb[2][128][17];        // 17 KB
  __shared__ int s_x, s_rk, s_R, s_ok;

  // ---- one-time: W-hi slabs -> LDS ----
  {
    const uint4* s0 = Whi0g + (size_t)bid * (KT0B * 64);
    for (int i = tid; i < KT0B * 64; i += THREADS) Wh0[i] = s0[i];
    const uint4* s1 = Whi1g + (size_t)bid * (KT1B * 64);
    for (int i = tid; i < KT1B * 64; i += THREADS) Wh1[i] = s1[i];
  }

  float bz0[4], bz1[4];
#pragma unroll
  for (int g = 0; g < 4; ++g) {
    bz0[g] = bias0[g * 1024 + ug];
    bz1[g] = bias1[g * 1024 + ug];
  }
  float c0r = 0.0f, c1r = 0.0f;           // cell states in registers

  // ---- bootstrap: XCD registration + first global sync (atomics, once) ----
  if (tid == 0) {
    s_ok = 1;
    int x = xcc_id();
    s_x = x;
    s_rk = atomicAdd(&ctr[F_CREG + x * 16], 1);
    vm_wait0();
    atomicAdd(&ctr[F_BOOT], 1);
    if (!spin_ge(&ctr[F_BOOT], NBLK)) s_ok = 0;
    int Rv = 1;
    for (int i = 0; i < 8; ++i) {
      int r = load_i32_llc(&ctr[F_CREG + i * 16]);
      if (i == s_x) Rv = r;
    }
    s_R = Rv;
  }
  __syncthreads();
  const int xcd = s_x, rk = s_rk, R = s_R;
  if (!s_ok) return;

  unsigned short* repB = rep + (size_t)xcd * 4 * HP;
  const unsigned short* A0Hb = repB;               // h0 hi
  const unsigned short* A0Lb = repB + HP;          // h0 lo
  const unsigned short* A1Hb = repB + 2 * HP;      // h1 hi
  const unsigned short* A1Lb = repB + 3 * HP;      // h1 lo
  const unsigned short* A0H = A0Hb + (size_t)arow * 1024;
  const unsigned short* A0L = A0Lb + (size_t)arow * 1024;
  const unsigned short* A1H = A1Hb + (size_t)arow * 1024;
  const unsigned short* A1L = A1Lb + (size_t)arow * 1024;

  // distribution role: plane pr, 16B chunk ch (pure linear copy)
  const int pr = tid >> 7;                // 0..3: h0hi,h0lo,h1hi,h1lo
  const int ch = (tid & 127) * 8;         // u16 offset
  const unsigned short* spBase =
      (pr == 0) ? hg0hi : (pr == 1) ? hg0lo : (pr == 2) ? hg1hi : hg1lo;
  unsigned short* dp = repB + pr * HP;
  const u32x4* wl0g = (const u32x4*)(Wlo0g + (size_t)bid * (KT0B * 64)) + lane;
  const u32x4* wl1g = (const u32x4*)(Wlo1g + (size_t)bid * (KT1B * 64)) + lane;

  for (int p = 0; p < NPH; ++p) {
    const int nact0 = (p < 512) ? ncnt[p] : 0;
    const int nact1 = (p >= 1) ? ncnt[p - 1] : 0;
    const bool doL0 = (p < 512) && (w * 16 < nact0);
    const bool doL1 = (p >= 1) && (w * 16 < nact1);

    f32x4 acc0 = (f32x4){0.f, 0.f, 0.f, 0.f};
    f32x4 acc1 = (f32x4){0.f, 0.f, 0.f, 0.f};

    // ---- (A) x-part GEMM (emb; L2-resident, no replica dep) ----
    if (doL0) {
      const int tok = ib[(size_t)permA * 512 + p];
      const unsigned short* eh = embHi + tok * 256;
      const unsigned short* el = embLo + tok * 256;
#pragma unroll
      for (int kt = 0; kt < 8; ++kt) {
        const bf16x8 ah = asbf(*(const u32x4*)(eh + kt * 32 + slotE));
        const bf16x8 al = asbf(*(const u32x4*)(el + kt * 32 + slotE));
        const bf16x8 bh = asbf4(Wh0[kt * 64 + lane]);
        const bf16x8 bl = asbf(__builtin_nontemporal_load(&wl0g[kt * 64]));
        MFMA3(acc0, ah, al, bh, bl)
      }
    }

    // ---- (B) distribute h0(p-1), h1(p-2) into XCD replica (linear copy) ----
    {
      const int ncopy = ncnt[p == 0 ? 0 : p - 1];
      const int par = (pr < 2) ? (p + 2) % 3 : (p + 1) % 3;
      const unsigned short* sp = spBase + (size_t)par * HP;
      for (int rb = rk; rb < ncopy; rb += 4 * R) {
        const int r1 = rb + R, r2 = rb + 2 * R, r3 = rb + 3 * R;
        uint4 v0, v1, v2, v3;
        v0 = llc_load_issue((const unsigned*)(sp + rb * 1024 + ch));
        if (r1 < ncopy) v1 = llc_load_issue((const unsigned*)(sp + r1 * 1024 + ch));
        if (r2 < ncopy) v2 = llc_load_issue((const unsigned*)(sp + r2 * 1024 + ch));
        if (r3 < ncopy) v3 = llc_load_issue((const unsigned*)(sp + r3 * 1024 + ch));
        vm_wait0();
        *(uint4*)(dp + rb * 1024 + ch) = v0;
        if (r1 < ncopy) *(uint4*)(dp + r1 * 1024 + ch) = v1;
        if (r2 < ncopy) *(uint4*)(dp + r2 * 1024 + ch) = v2;
        if (r3 < ncopy) *(uint4*)(dp + r3 * 1024 + ch) = v3;
      }
    }
    __syncthreads();                      // drains stores (implicit vmcnt(0))

    // ---- (C) XCD barrier: 1 round (all blocks poll all arrive flags) ----
    if (tid == 0) store_u32_llc((unsigned*)&ctr[F_XARR + xcd * 32 + rk], p + 1);
    if (tid < 32 && tid < R) {
      if (!spin_ge(&ctr[F_XARR + xcd * 32 + tid], p + 1)) s_ok = 0;
    }
    __syncthreads();
    if (!s_ok) break;
    inv_l1();                             // fresh L1 view of replica

    // ---- (D) h-part GEMMs, register-pipelined (PF=4, double-buffered) ----
    if (doL0 && doL1) {
      u32x4 aH[2][4], aL[2][4], w0[2][4], w1[2][4];
      auto ldg = [&](int buf, int g) {
#pragma unroll
        for (int i = 0; i < 4; ++i) {
          const int q = g * 4 + i;
          aH[buf][i] = *(const u32x4*)(A0H + q * 32 + slotE);
          aL[buf][i] = *(const u32x4*)(A0L + q * 32 + slotE);
          w0[buf][i] = __builtin_nontemporal_load(&wl0g[(q + 8) * 64]);
          w1[buf][i] = __builtin_nontemporal_load(&wl1g[q * 64]);
        }
      };
      ldg(0, 0);
#pragma unroll
      for (int g = 0; g < 8; ++g) {
        const int cb = g & 1;
        if (g < 7) ldg(cb ^ 1, g + 1);
#pragma unroll
        for (int i = 0; i < 4; ++i) {
          const int q = g * 4 + i;
          const bf16x8 ah = asbf(aH[cb][i]), al = asbf(aL[cb][i]);
          const bf16x8 b0h = asbf4(Wh0[(q + 8) * 64 + lane]), b0l = asbf(w0[cb][i]);
          const bf16x8 b1h = asbf4(Wh1[q * 64 + lane]),       b1l = asbf(w1[cb][i]);
          MFMA3(acc0, ah, al, b0h, b0l)
          MFMA3(acc1, ah, al, b1h, b1l)
        }
      }
    } else if (doL0) {
#pragma unroll 4
      for (int q = 0; q < 32; ++q) {
        const bf16x8 ah = asbf(*(const u32x4*)(A0H + q * 32 + slotE));
        const bf16x8 al = asbf(*(const u32x4*)(A0L + q * 32 + slotE));
        const bf16x8 bh = asbf4(Wh0[(q + 8) * 64 + lane]);
        const bf16x8 bl = asbf(__builtin_nontemporal_load(&wl0g[(q + 8) * 64]));
        MFMA3(acc0, ah, al, bh, bl)
      }
    } else if (doL1) {
#pragma unroll 4
      for (int q = 0; q < 32; ++q) {
        const bf16x8 ah = asbf(*(const u32x4*)(A0H + q * 32 + slotE));
        const bf16x8 al = asbf(*(const u32x4*)(A0L + q * 32 + slotE));
        const bf16x8 bh = asbf4(Wh1[q * 64 + lane]);
        const bf16x8 bl = asbf(__builtin_nontemporal_load(&wl1g[q * 64]));
        MFMA3(acc1, ah, al, bh, bl)
      }
    }
    if (doL1) {                           // h1 part, pipelined
      u32x4 aH[2][4], aL[2][4], w1[2][4];
      auto ldg = [&](int buf, int g) {
#pragma unroll
        for (int i = 0; i < 4; ++i) {
          const int q = g * 4 + i;
          aH[buf][i] = *(const u32x4*)(A1H + q * 32 + slotE);
          aL[buf][i] = *(const u32x4*)(A1L + q * 32 + slotE);
          w1[buf][i] = __builtin_nontemporal_load(&wl1g[(q + 32) * 64]);
        }
      };
      ldg(0, 0);
#pragma unroll
      for (int g = 0; g < 8; ++g) {
        const int cb = g & 1;
        if (g < 7) ldg(cb ^ 1, g + 1);
#pragma unroll
        for (int i = 0; i < 4; ++i) {
          const int q = g * 4 + i;
          const bf16x8 ah = asbf(aH[cb][i]), al = asbf(aL[cb][i]);
          const bf16x8 bh = asbf4(Wh1[(q + 32) * 64 + lane]), bl = asbf(w1[cb][i]);
          MFMA3(acc1, ah, al, bh, bl)
        }
      }
    }

    // ---- (E) z exchange (C/D: row = 4*(l>>4)+reg, col = l&15) ----
    if (doL0) {
#pragma unroll
      for (int rr = 0; rr < 4; ++rr) zb[0][w * 16 + lg4 + rr][lr] = acc0[rr];
    }
    if (doL1) {
#pragma unroll
      for (int rr = 0; rr < 4; ++rr) zb[1][w * 16 + lg4 + rr][lr] = acc1[rr];
    }
    __syncthreads();

    // ---- (F) fused cells (thread = row x unit), frag-order h stores ----
    if (p < 512 && p < clen) {            // L0, t = p
      const float zi = zb[0][srow][cu * 4 + 0] + bz0[0];
      const float zj = zb[0][srow][cu * 4 + 1] + bz0[1];
      const float zf = zb[0][srow][cu * 4 + 2] + bz0[2];
      const float zo = zb[0][srow][cu * 4 + 3] + bz0[3];
      const float nc = c0r * sigm(zf + 1.0f) + sigm(zi) * tanh_f(zj);
      const float nh = tanh_f(nc) * sigm(zo);
      c0r = nc;
      const unsigned short hh = f2bf(nh);
      const unsigned short hl = f2bf(nh - bf2f(hh));
      const size_t idx = (size_t)(p % 3) * HP + srow * 1024 + fpos;
      store_u16_llc(&hg0hi[idx], hh);
      store_u16_llc(&hg0lo[idx], hl);
    }
    if (p >= 1 && (p - 1) < clen) {       // L1, t = p-1
      const float zi = zb[1][srow][cu * 4 + 0] + bz1[0];
      const float zj = zb[1][srow][cu * 4 + 1] + bz1[1];
      const float zf = zb[1][srow][cu * 4 + 2] + bz1[2];
      const float zo = zb[1][srow][cu * 4 + 3] + bz1[3];
      const float nc = c1r * sigm(zf + 1.0f) + sigm(zi) * tanh_f(zj);
      const float nh = tanh_f(nc) * sigm(zo);
      c1r = nc;
      const unsigned short hh = f2bf(nh);
      const unsigned short hl = f2bf(nh - bf2f(hh));
      const size_t idx = (size_t)((p + 2) % 3) * HP + srow * 1024 + fpos;
      store_u16_llc(&hg1hi[idx], hh);
      store_u16_llc(&hg1lo[idx], hl);
      if (p - 1 == clen - 1) out[(size_t)cperm * 1024 + ug] = nh;
    }

    // ---- (G) global barrier (flag-based, leader + GO) ----
    vm_wait0();                           // h stores LLC-visible
    __syncthreads();
    if (tid == 0) store_u32_llc((unsigned*)&ctr[F_ARR + bid], p + 1);
    if (bid == 0) {
      if (tid < 256) {
        if (!spin_ge(&ctr[F_ARR + tid], p + 1)) s_ok = 0;
      }
      __syncthreads();
      if (tid == 0) store_u32_llc((unsigned*)&ctr[F_GO], p + 1);
    }
    if (tid == 0) {
      if (!spin_ge(&ctr[F_GO], p + 1)) s_ok = 0;
    }
    __syncthreads();
    if (!s_ok) break;
  }
}

// ======================= host launch =======================================

extern "C" void kernel_launch(void* const* d_in, const int* in_sizes, int n_in,
                              void* d_out, int out_size, void* d_ws, size_t ws_size,
                              hipStream_t stream) {
  const int*   ib   = (const int*)d_in[0];
  const int*   lens = (const int*)d_in[1];
  const float* emb  = (const float*)d_in[2];
  const float* W0   = (const float*)d_in[3];
  const float* b0   = (const float*)d_in[4];
  const float* W1   = (const float*)d_in[5];
  const float* b1   = (const float*)d_in[6];
  (void)in_sizes; (void)n_in; (void)out_size; (void)ws_size;

  char* ws = (char*)d_ws;
  size_t off = 0;
  auto alloc = [&](size_t bytes) { char* q = ws + off; off += (bytes + 255) & ~(size_t)255; return q; };

  int*            ctr   = (int*)alloc(4096);
  unsigned short* hg0hi = (unsigned short*)alloc((size_t)3 * HP * 2);
  unsigned short* hg0lo = (unsigned short*)alloc((size_t)3 * HP * 2);
  unsigned short* hg1hi = (unsigned short*)alloc((size_t)3 * HP * 2);
  unsigned short* hg1lo = (unsigned short*)alloc((size_t)3 * HP * 2);
  const size_t zero_bytes = off;          // ctr + h planes
  unsigned short* embHi = (unsigned short*)alloc(128 * 256 * 2);
  unsigned short* embLo = (unsigned short*)alloc(128 * 256 * 2);
  int*            perm  = (int*)alloc(4096);   // perm[128], lenS[128], ncnt[512]
  int*            lenS  = perm + 128;
  int*            ncnt  = perm + 256;
  unsigned short* rep   = (unsigned short*)alloc((size_t)8 * 4 * HP * 2);
  uint4*          Whi0  = (uint4*)alloc((size_t)NBLK * KT0B * 64 * 16);
  uint4*          Wlo0  = (uint4*)alloc((size_t)NBLK * KT0B * 64 * 16);
  uint4*          Whi1  = (uint4*)alloc((size_t)NBLK * KT1B * 64 * 16);
  uint4*          Wlo1  = (uint4*)alloc((size_t)NBLK * KT1B * 64 * 16);

  hipMemsetAsync(d_ws, 0, zero_bytes, stream);
  prep_sort<<<1, 512, 0, stream>>>(lens, perm, lenS, ncnt);
  prep_emb<<<128, 256, 0, stream>>>(emb, embHi, embLo);
  prep_wslab<<<(NBLK * KT0B * 64) / 256, 256, 0, stream>>>(W0, Whi0, Wlo0, KT0B);
  prep_wslab<<<(NBLK * KT1B * 64) / 256, 256, 0, stream>>>(W1, Whi1, Wlo1, KT1B);
  lstm_persist<<<NBLK, THREADS, 0, stream>>>(
      ib, b0, b1, Whi0, Wlo0, Whi1, Wlo1, embHi, embLo,
      perm, lenS, ncnt, hg0hi, hg0lo, hg1hi, hg1lo, rep, ctr, (float*)d_out);
}

// Round 7
// 20047.395 us; speedup vs baseline: 1.5035x; 1.2536x over previous
//
#include <hip/hip_runtime.h>

// ---------------------------------------------------------------------------
// 2-layer LSTM encoder, B=128 T=512 E=256 H=1024 (round 7).
// Persistent kernel: 256 blocks x 512 threads (8 waves, fused dual-layer).
// Per phase p: L0 (t=p): z0=[x_p;h0(p-1)]@W0 -> h0(p)
//             L1 (t=p-1): z1=[h0(p-1);h1(p-2)]@W1 -> h1(p-1)
// Split-bf16 x3 MFMA (verified r1-r6). W-hi LDS-resident; W-lo streamed.
// NEW r7 (attacking latency-serialization, the session-long bottleneck):
//  - __launch_bounds__(512,1): 256 VGPR/wave so the 2x(4kt x 4stream)
//    prefetch buffers live in registers (~16 loads in flight/wave).
//    Prior rounds' caps (88/52/128 VGPR) forced depth ~2-4 -> ~45us phases.
//  - plain W-lo loads (no nt): L1 serves the 8-wave reuse.
//  - dist loads issued BEFORE x-part GEMM (latency overlapped), stores after.
//  - next-phase x-part W-lo prefetched into regs during global-barrier spin.
// ---------------------------------------------------------------------------

namespace {
constexpr int NBLK = 256, THREADS = 512;
constexpr int KT0B = 40;           // L0 k-tiles of 32 (K=1280)
constexpr int KT1B = 64;           // L1 k-tiles of 32 (K=2048)
constexpr int NPH = 513;
constexpr int HP = 128 * 1024;     // u16 elems per h plane
constexpr int SPIN_CAP = 2000000;
// flag slots (u32 index into ctr[1024], all zeroed per launch)
constexpr int F_CREG = 0;          // 8 x 16 (boot atomics)
constexpr int F_BOOT = 128;
constexpr int F_ARR  = 256;        // 256 contiguous
constexpr int F_GO   = 520;
constexpr int F_XARR = 576;        // 8 x 32
}

typedef __bf16 bf16x8 __attribute__((ext_vector_type(8)));
typedef float f32x4 __attribute__((ext_vector_type(4)));
typedef unsigned u32x4 __attribute__((ext_vector_type(4)));

__host__ __device__ __forceinline__ int fswz(int kk) {   // frag order within 32
  return ((kk & 15) >> 2) * 8 + (kk >> 4) * 4 + (kk & 3);
}

__device__ __forceinline__ unsigned short f2bf(float f) {
  unsigned u = __float_as_uint(f);
  u += 0x7fffu + ((u >> 16) & 1u);
  return (unsigned short)(u >> 16);
}
__device__ __forceinline__ float bf2f(unsigned short h) {
  return __uint_as_float(((unsigned)h) << 16);
}
__device__ __forceinline__ float sigm(float x) { return 1.0f / (1.0f + __expf(-x)); }
__device__ __forceinline__ float tanh_f(float x) {
  float e = __expf(-2.0f * fabsf(x));
  float r = (1.0f - e) / (1.0f + e);
  return x >= 0.0f ? r : -r;
}

// ---- LLC-coherent ops (bypass L1+L2) --------------------------------------
__device__ __forceinline__ int load_i32_llc(const int* p) {
  int v;
  asm volatile("global_load_dword %0, %1, off sc0 sc1\n\ts_waitcnt vmcnt(0)"
               : "=v"(v) : "v"(p) : "memory");
  return v;
}
__device__ __forceinline__ uint4 llc_load_issue(const unsigned* p) {
  uint4 v;
  asm volatile("global_load_dwordx4 %0, %1, off sc0 sc1" : "=v"(v) : "v"(p));
  return v;
}
__device__ __forceinline__ void vm_wait0() {
  asm volatile("s_waitcnt vmcnt(0)" ::: "memory");
  __builtin_amdgcn_sched_barrier(0);
}
__device__ __forceinline__ void store_u32_llc(unsigned* p, unsigned v) {
  asm volatile("global_store_dword %0, %1, off sc0 sc1" :: "v"(p), "v"(v) : "memory");
}
__device__ __forceinline__ void store_u16_llc(unsigned short* p, unsigned short v) {
  asm volatile("global_store_short %0, %1, off sc0 sc1" :: "v"(p), "v"(v) : "memory");
}
__device__ __forceinline__ void inv_l1() {
  asm volatile("buffer_inv" ::: "memory");
}
__device__ __forceinline__ int xcc_id() {
  int x;
  asm("s_getreg_b32 %0, hwreg(HW_REG_XCC_ID)" : "=s"(x));
  return x & 7;
}
__device__ __forceinline__ int spin_ge(int* p, int target) {
  for (int it = 0; it < SPIN_CAP; ++it) {
    if (load_i32_llc(p) >= target) return 1;
    __builtin_amdgcn_s_sleep(1);
  }
  return 0;
}
__device__ __forceinline__ bf16x8 asbf(u32x4 v) { return __builtin_bit_cast(bf16x8, v); }
__device__ __forceinline__ bf16x8 asbf4(uint4 v) { return __builtin_bit_cast(bf16x8, v); }

#define MFMA3(acc, ah, al, bh, bl)                                            \
  acc = __builtin_amdgcn_mfma_f32_16x16x32_bf16(ah, bh, acc, 0, 0, 0);        \
  acc = __builtin_amdgcn_mfma_f32_16x16x32_bf16(ah, bl, acc, 0, 0, 0);        \
  acc = __builtin_amdgcn_mfma_f32_16x16x32_bf16(al, bh, acc, 0, 0, 0);

// ======================= prep kernels =====================================

__global__ void prep_sort(const int* __restrict__ lens, int* __restrict__ perm,
                          int* __restrict__ lenS, int* __restrict__ ncnt) {
  __shared__ int k_[128], p_[128];
  const int tid = threadIdx.x;
  if (tid < 128) { k_[tid] = (lens[tid] << 8) | (127 - tid); p_[tid] = tid; }
  __syncthreads();
  for (int ph = 0; ph < 128; ++ph) {
    if (tid < 64) {
      int a = 2 * tid + (ph & 1), b = a + 1;
      if (b < 128 && k_[a] < k_[b]) {
        int tk = k_[a]; k_[a] = k_[b]; k_[b] = tk;
        int tp = p_[a]; p_[a] = p_[b]; p_[b] = tp;
      }
    }
    __syncthreads();
  }
  if (tid < 128) { perm[tid] = p_[tid]; lenS[tid] = k_[tid] >> 8; }
  if (tid < 512) {
    int c = 0;
    for (int i = 0; i < 128; ++i) c += ((k_[i] >> 8) > tid) ? 1 : 0;
    ncnt[tid] = c;
  }
}

// emb planes in fragment-interleaved order
__global__ void prep_emb(const float* __restrict__ emb,
                         unsigned short* __restrict__ ehi,
                         unsigned short* __restrict__ elo) {
  int i = blockIdx.x * 256 + threadIdx.x;   // 32768
  int row = i >> 8, e = i & 255;
  int pos = row * 256 + (e >> 5) * 32 + fswz(e & 31);
  float f = emb[i];
  unsigned short h = f2bf(f);
  ehi[pos] = h;
  elo[pos] = f2bf(f - bf2f(h));
}

// W[k][4096] -> per-block frag slabs: e = (blk*KT + kt)*64 + lane.
// lane: cf = lane&15 = u_local*4 + g ; col = g*1024 + blk*4 + u_local
// elem j: k = kt*32 + ((lane>>4)&3)*4 + (j&3) + 16*(j>>2)
__global__ void prep_wslab(const float* __restrict__ W, uint4* __restrict__ Whi,
                           uint4* __restrict__ Wlo, int KT) {
  int e = blockIdx.x * 256 + threadIdx.x;
  int lane = e & 63;
  int kt = (e >> 6) % KT;
  int blk = e / (64 * KT);
  int cf = lane & 15;
  int g = cf & 3, ul = cf >> 2;
  int col = g * 1024 + blk * 4 + ul;
  int kbase = kt * 32 + ((lane >> 4) & 3) * 4;
  unsigned hi[8], lo[8];
#pragma unroll
  for (int j = 0; j < 8; ++j) {
    int k = kbase + (j & 3) + 16 * (j >> 2);
    float f = W[(size_t)k * 4096 + col];
    unsigned short h = f2bf(f);
    hi[j] = h;
    lo[j] = f2bf(f - bf2f(h));
  }
  uint4 vh, vl;
  vh.x = hi[0] | (hi[1] << 16); vh.y = hi[2] | (hi[3] << 16);
  vh.z = hi[4] | (hi[5] << 16); vh.w = hi[6] | (hi[7] << 16);
  vl.x = lo[0] | (lo[1] << 16); vl.y = lo[2] | (lo[3] << 16);
  vl.z = lo[4] | (lo[5] << 16); vl.w = lo[6] | (lo[7] << 16);
  Whi[e] = vh;
  Wlo[e] = vl;
}

// ======================= persistent kernel =================================

__global__ __launch_bounds__(THREADS, 1) void lstm_persist(
    const int* __restrict__ ib,
    const float* __restrict__ bias0, const float* __restrict__ bias1,
    const uint4* __restrict__ Whi0g, const uint4* __restrict__ Wlo0g,
    const uint4* __restrict__ Whi1g, const uint4* __restrict__ Wlo1g,
    const unsigned short* __restrict__ embHi, const unsigned short* __restrict__ embLo,
    const int* __restrict__ perm, const int* __restrict__ lenS,
    const int* __restrict__ ncnt,
    unsigned short* hg0hi, unsigned short* hg0lo,   // [3][128][1024] frag-order
    unsigned short* hg1hi, unsigned short* hg1lo,
    unsigned short* rep,                            // [8][4][128][1024]
    int* ctr, float* __restrict__ out) {
  const int bid = blockIdx.x;
  const int tid = threadIdx.x;
  const int w = tid >> 6;                 // wave 0..7 -> rows w*16..+15
  const int lane = tid & 63;
  const int lr = lane & 15;
  const int lg4 = ((lane >> 4) & 3) * 4;
  const int slotE = ((lane >> 4) & 3) * 8;  // frag u16 offset within 32-group
  const int arow = w * 16 + lr;           // GEMM A row for this lane
  const int srow = tid >> 2;              // cell row 0..127
  const int cu = tid & 3;                 // cell unit 0..3
  const int ug = bid * 4 + cu;            // global unit
  const int fpos = (ug >> 5) * 32 + fswz(ug & 31);  // frag pos of unit in row
  const int permA = perm[arow];
  const int cperm = perm[srow];
  const int clen = lenS[srow];

  __shared__ uint4 Wh0[KT0B * 64];        // 40 KB
  __shared__ uint4 Wh1[KT1B * 64];        // 64 KB
  __shared__ float zb[2][128][17];        // 17 KB
  __shared__ int s_x, s_rk, s_R, s_ok;

  // ---- one-time: W-hi slabs -> LDS ----
  {
    const uint4* s0 = Whi0g + (size_t)bid * (KT0B * 64);
    for (int i = tid; i < KT0B * 64; i += THREADS) Wh0[i] = s0[i];
    const uint4* s1 = Whi1g + (size_t)bid * (KT1B * 64);
    for (int i = tid; i < KT1B * 64; i += THREADS) Wh1[i] = s1[i];
  }

  float bz0[4], bz1[4];
#pragma unroll
  for (int g = 0; g < 4; ++g) {
    bz0[g] = bias0[g * 1024 + ug];
    bz1[g] = bias1[g * 1024 + ug];
  }
  float c0r = 0.0f, c1r = 0.0f;           // cell states in registers

  // ---- bootstrap: XCD registration + first global sync (atomics, once) ----
  if (tid == 0) {
    s_ok = 1;
    int x = xcc_id();
    s_x = x;
    s_rk = atomicAdd(&ctr[F_CREG + x * 16], 1);
    vm_wait0();
    atomicAdd(&ctr[F_BOOT], 1);
    if (!spin_ge(&ctr[F_BOOT], NBLK)) s_ok = 0;
    int Rv = 1;
    for (int i = 0; i < 8; ++i) {
      int r = load_i32_llc(&ctr[F_CREG + i * 16]);
      if (i == s_x) Rv = r;
    }
    s_R = Rv;
  }
  __syncthreads();
  const int xcd = s_x, rk = s_rk, R = s_R;
  if (!s_ok) return;

  unsigned short* repB = rep + (size_t)xcd * 4 * HP;
  const unsigned short* A0H = repB + (size_t)arow * 1024;
  const unsigned short* A0L = repB + HP + (size_t)arow * 1024;
  const unsigned short* A1H = repB + 2 * HP + (size_t)arow * 1024;
  const unsigned short* A1L = repB + 3 * HP + (size_t)arow * 1024;

  // distribution role: plane pr, 16B chunk ch (pure linear copy)
  const int pr = tid >> 7;                // 0..3: h0hi,h0lo,h1hi,h1lo
  const int ch = (tid & 127) * 8;         // u16 offset
  const unsigned short* spBase =
      (pr == 0) ? hg0hi : (pr == 1) ? hg0lo : (pr == 2) ? hg1hi : hg1lo;
  unsigned short* dp = repB + pr * HP;
  const u32x4* wl0g = (const u32x4*)(Wlo0g + (size_t)bid * (KT0B * 64)) + lane;
  const u32x4* wl1g = (const u32x4*)(Wlo1g + (size_t)bid * (KT1B * 64)) + lane;

  // x-part W-lo prefetch (constant data; refreshed during barrier spin)
  u32x4 xw[8];
#pragma unroll
  for (int kt = 0; kt < 8; ++kt) xw[kt] = wl0g[kt * 64];

  for (int p = 0; p < NPH; ++p) {
    const int nact0 = (p < 512) ? ncnt[p] : 0;
    const int nact1 = (p >= 1) ? ncnt[p - 1] : 0;
    const bool doL0 = (p < 512) && (w * 16 < nact0);
    const bool doL1 = (p >= 1) && (w * 16 < nact1);

    f32x4 acc0 = (f32x4){0.f, 0.f, 0.f, 0.f};
    f32x4 acc1 = (f32x4){0.f, 0.f, 0.f, 0.f};

    // ---- (A) dist: ISSUE LLC loads (complete under x-part compute) ----
    const int ncopy = ncnt[p == 0 ? 0 : p - 1];
    const int par = (pr < 2) ? (p + 2) % 3 : (p + 1) % 3;
    const unsigned short* sp = spBase + (size_t)par * HP;
    uint4 dv0, dv1, dv2, dv3;
    const int dr0 = rk, dr1 = rk + R, dr2 = rk + 2 * R, dr3 = rk + 3 * R;
    if (dr0 < ncopy) dv0 = llc_load_issue((const unsigned*)(sp + dr0 * 1024 + ch));
    if (dr1 < ncopy) dv1 = llc_load_issue((const unsigned*)(sp + dr1 * 1024 + ch));
    if (dr2 < ncopy) dv2 = llc_load_issue((const unsigned*)(sp + dr2 * 1024 + ch));
    if (dr3 < ncopy) dv3 = llc_load_issue((const unsigned*)(sp + dr3 * 1024 + ch));

    // ---- (B) x-part GEMM (emb; W-lo from prefetched regs) ----
    if (doL0) {
      const int tok = ib[(size_t)permA * 512 + p];
      const unsigned short* eh = embHi + tok * 256;
      const unsigned short* el = embLo + tok * 256;
#pragma unroll
      for (int kt = 0; kt < 8; ++kt) {
        const bf16x8 ah = asbf(*(const u32x4*)(eh + kt * 32 + slotE));
        const bf16x8 al = asbf(*(const u32x4*)(el + kt * 32 + slotE));
        const bf16x8 bh = asbf4(Wh0[kt * 64 + lane]);
        const bf16x8 bl = asbf(xw[kt]);
        MFMA3(acc0, ah, al, bh, bl)
      }
    }

    // ---- (C) finish dist: wait + store into replica (plain L2 stores) ----
    vm_wait0();
    if (dr0 < ncopy) *(uint4*)(dp + dr0 * 1024 + ch) = dv0;
    if (dr1 < ncopy) *(uint4*)(dp + dr1 * 1024 + ch) = dv1;
    if (dr2 < ncopy) *(uint4*)(dp + dr2 * 1024 + ch) = dv2;
    if (dr3 < ncopy) *(uint4*)(dp + dr3 * 1024 + ch) = dv3;
    for (int r = rk + 4 * R; r < ncopy; r += R) {     // safety (R<32 only)
      uint4 v = llc_load_issue((const unsigned*)(sp + r * 1024 + ch));
      vm_wait0();
      *(uint4*)(dp + r * 1024 + ch) = v;
    }
    __syncthreads();                      // drains stores

    // ---- (D) XCD barrier: 1 round (all blocks poll all arrive flags) ----
    if (tid == 0) store_u32_llc((unsigned*)&ctr[F_XARR + xcd * 32 + rk], p + 1);
    if (tid < 32 && tid < R) {
      if (!spin_ge(&ctr[F_XARR + xcd * 32 + tid], p + 1)) s_ok = 0;
    }
    __syncthreads();
    if (!s_ok) break;
    inv_l1();                             // fresh L1 view of replica

    // ---- (E) h-part GEMMs, register-pipelined (PF=4, double-buffered) ----
    if (doL0 && doL1) {
      u32x4 aH[2][4], aL[2][4], w0[2][4], w1[2][4];
      auto ldg = [&](int buf, int g) {
#pragma unroll
        for (int i = 0; i < 4; ++i) {
          const int q = g * 4 + i;
          aH[buf][i] = *(const u32x4*)(A0H + q * 32 + slotE);
          aL[buf][i] = *(const u32x4*)(A0L + q * 32 + slotE);
          w0[buf][i] = wl0g[(q + 8) * 64];
          w1[buf][i] = wl1g[q * 64];
        }
      };
      ldg(0, 0);
#pragma unroll
      for (int g = 0; g < 8; ++g) {
        const int cb = g & 1;
        if (g < 7) ldg(cb ^ 1, g + 1);
#pragma unroll
        for (int i = 0; i < 4; ++i) {
          const int q = g * 4 + i;
          const bf16x8 ah = asbf(aH[cb][i]), al = asbf(aL[cb][i]);
          const bf16x8 b0h = asbf4(Wh0[(q + 8) * 64 + lane]), b0l = asbf(w0[cb][i]);
          const bf16x8 b1h = asbf4(Wh1[q * 64 + lane]),       b1l = asbf(w1[cb][i]);
          MFMA3(acc0, ah, al, b0h, b0l)
          MFMA3(acc1, ah, al, b1h, b1l)
        }
      }
    } else if (doL0) {
#pragma unroll 4
      for (int q = 0; q < 32; ++q) {
        const bf16x8 ah = asbf(*(const u32x4*)(A0H + q * 32 + slotE));
        const bf16x8 al = asbf(*(const u32x4*)(A0L + q * 32 + slotE));
        const bf16x8 bh = asbf4(Wh0[(q + 8) * 64 + lane]);
        const bf16x8 bl = asbf(wl0g[(q + 8) * 64]);
        MFMA3(acc0, ah, al, bh, bl)
      }
    } else if (doL1) {
#pragma unroll 4
      for (int q = 0; q < 32; ++q) {
        const bf16x8 ah = asbf(*(const u32x4*)(A0H + q * 32 + slotE));
        const bf16x8 al = asbf(*(const u32x4*)(A0L + q * 32 + slotE));
        const bf16x8 bh = asbf4(Wh1[q * 64 + lane]);
        const bf16x8 bl = asbf(wl1g[q * 64]);
        MFMA3(acc1, ah, al, bh, bl)
      }
    }
    if (doL1) {                           // h1 part, pipelined
      u32x4 aH[2][4], aL[2][4], w1[2][4];
      auto ldg = [&](int buf, int g) {
#pragma unroll
        for (int i = 0; i < 4; ++i) {
          const int q = g * 4 + i;
          aH[buf][i] = *(const u32x4*)(A1H + q * 32 + slotE);
          aL[buf][i] = *(const u32x4*)(A1L + q * 32 + slotE);
          w1[buf][i] = wl1g[(q + 32) * 64];
        }
      };
      ldg(0, 0);
#pragma unroll
      for (int g = 0; g < 8; ++g) {
        const int cb = g & 1;
        if (g < 7) ldg(cb ^ 1, g + 1);
#pragma unroll
        for (int i = 0; i < 4; ++i) {
          const int q = g * 4 + i;
          const bf16x8 ah = asbf(aH[cb][i]), al = asbf(aL[cb][i]);
          const bf16x8 bh = asbf4(Wh1[(q + 32) * 64 + lane]), bl = asbf(w1[cb][i]);
          MFMA3(acc1, ah, al, bh, bl)
        }
      }
    }

    // ---- (F) z exchange (C/D: row = 4*(l>>4)+reg, col = l&15) ----
    if (doL0) {
#pragma unroll
      for (int rr = 0; rr < 4; ++rr) zb[0][w * 16 + lg4 + rr][lr] = acc0[rr];
    }
    if (doL1) {
#pragma unroll
      for (int rr = 0; rr < 4; ++rr) zb[1][w * 16 + lg4 + rr][lr] = acc1[rr];
    }
    __syncthreads();

    // ---- (G) fused cells (thread = row x unit), frag-order h stores ----
    if (p < 512 && p < clen) {            // L0, t = p
      const float zi = zb[0][srow][cu * 4 + 0] + bz0[0];
      const float zj = zb[0][srow][cu * 4 + 1] + bz0[1];
      const float zf = zb[0][srow][cu * 4 + 2] + bz0[2];
      const float zo = zb[0][srow][cu * 4 + 3] + bz0[3];
      const float nc = c0r * sigm(zf + 1.0f) + sigm(zi) * tanh_f(zj);
      const float nh = tanh_f(nc) * sigm(zo);
      c0r = nc;
      const unsigned short hh = f2bf(nh);
      const unsigned short hl = f2bf(nh - bf2f(hh));
      const size_t idx = (size_t)(p % 3) * HP + srow * 1024 + fpos;
      store_u16_llc(&hg0hi[idx], hh);
      store_u16_llc(&hg0lo[idx], hl);
    }
    if (p >= 1 && (p - 1) < clen) {       // L1, t = p-1
      const float zi = zb[1][srow][cu * 4 + 0] + bz1[0];
      const float zj = zb[1][srow][cu * 4 + 1] + bz1[1];
      const float zf = zb[1][srow][cu * 4 + 2] + bz1[2];
      const float zo = zb[1][srow][cu * 4 + 3] + bz1[3];
      const float nc = c1r * sigm(zf + 1.0f) + sigm(zi) * tanh_f(zj);
      const float nh = tanh_f(nc) * sigm(zo);
      c1r = nc;
      const unsigned short hh = f2bf(nh);
      const unsigned short hl = f2bf(nh - bf2f(hh));
      const size_t idx = (size_t)((p + 2) % 3) * HP + srow * 1024 + fpos;
      store_u16_llc(&hg1hi[idx], hh);
      store_u16_llc(&hg1lo[idx], hl);
      if (p - 1 == clen - 1) out[(size_t)cperm * 1024 + ug] = nh;
    }

    // ---- (H) global barrier; prefetch next x-part W-lo during spin ----
    vm_wait0();                           // h stores LLC-visible
    __syncthreads();
    if (tid == 0) store_u32_llc((unsigned*)&ctr[F_ARR + bid], p + 1);
#pragma unroll
    for (int kt = 0; kt < 8; ++kt) xw[kt] = wl0g[kt * 64];  // constant data
    if (bid == 0) {
      if (tid < 256) {
        if (!spin_ge(&ctr[F_ARR + tid], p + 1)) s_ok = 0;
      }
      __syncthreads();
      if (tid == 0) store_u32_llc((unsigned*)&ctr[F_GO], p + 1);
    }
    if (tid == 0) {
      if (!spin_ge(&ctr[F_GO], p + 1)) s_ok = 0;
    }
    __syncthreads();
    if (!s_ok) break;
  }
}

// ======================= host launch =======================================

extern "C" void kernel_launch(void* const* d_in, const int* in_sizes, int n_in,
                              void* d_out, int out_size, void* d_ws, size_t ws_size,
                              hipStream_t stream) {
  const int*   ib   = (const int*)d_in[0];
  const int*   lens = (const int*)d_in[1];
  const float* emb  = (const float*)d_in[2];
  const float* W0   = (const float*)d_in[3];
  const float* b0   = (const float*)d_in[4];
  const float* W1   = (const float*)d_in[5];
  const float* b1   = (const float*)d_in[6];
  (void)in_sizes; (void)n_in; (void)out_size; (void)ws_size;

  char* ws = (char*)d_ws;
  size_t off = 0;
  auto alloc = [&](size_t bytes) { char* q = ws + off; off += (bytes + 255) & ~(size_t)255; return q; };

  int*            ctr   = (int*)alloc(4096);
  unsigned short* hg0hi = (unsigned short*)alloc((size_t)3 * HP * 2);
  unsigned short* hg0lo = (unsigned short*)alloc((size_t)3 * HP * 2);
  unsigned short* hg1hi = (unsigned short*)alloc((size_t)3 * HP * 2);
  unsigned short* hg1lo = (unsigned short*)alloc((size_t)3 * HP * 2);
  const size_t zero_bytes = off;          // ctr + h planes
  unsigned short* embHi = (unsigned short*)alloc(128 * 256 * 2);
  unsigned short* embLo = (unsigned short*)alloc(128 * 256 * 2);
  int*            perm  = (int*)alloc(4096);   // perm[128], lenS[128], ncnt[512]
  int*            lenS  = perm + 128;
  int*            ncnt  = perm + 256;
  unsigned short* rep   = (unsigned short*)alloc((size_t)8 * 4 * HP * 2);
  uint4*          Whi0  = (uint4*)alloc((size_t)NBLK * KT0B * 64 * 16);
  uint4*          Wlo0  = (uint4*)alloc((size_t)NBLK * KT0B * 64 * 16);
  uint4*          Whi1  = (uint4*)alloc((size_t)NBLK * KT1B * 64 * 16);
  uint4*          Wlo1  = (uint4*)alloc((size_t)NBLK * KT1B * 64 * 16);

  hipMemsetAsync(d_ws, 0, zero_bytes, stream);
  prep_sort<<<1, 512, 0, stream>>>(lens, perm, lenS, ncnt);
  prep_emb<<<128, 256, 0, stream>>>(emb, embHi, embLo);
  prep_wslab<<<(NBLK * KT0B * 64) / 256, 256, 0, stream>>>(W0, Whi0, Wlo0, KT0B);
  prep_wslab<<<(NBLK * KT1B * 64) / 256, 256, 0, stream>>>(W1, Whi1, Wlo1, KT1B);
  lstm_persist<<<NBLK, THREADS, 0, stream>>>(
      ib, b0, b1, Whi0, Wlo0, Whi1, Wlo1, embHi, embLo,
      perm, lenS, ncnt, hg0hi, hg0lo, hg1hi, hg1lo, rep, ctr, (float*)d_out);
}

// Round 8
// 17195.052 us; speedup vs baseline: 1.7529x; 1.1659x over previous
//
#include <hip/hip_runtime.h>

// ---------------------------------------------------------------------------
// 2-layer LSTM encoder, B=128 T=512 E=256 H=1024 (round 8).
// Persistent kernel: 256 blocks x 512 threads (8 waves, fused dual-layer).
// Per phase p: L0 (t=p): z0=[x_p;h0(p-1)]@W0 -> h0(p)
//             L1 (t=p-1): z1=[h0(p-1);h1(p-2)]@W1 -> h1(p-1)
// Split-bf16 x3 MFMA (verified r1-r7). W-hi LDS-resident (104 KB, once).
// NEW r8: W-lo staged per-phase into LDS via async global_load_lds
// (dwordx4), 13 chunks of 8x1KB (one gll per wave per chunk), double-
// buffered. Removes W-lo from VGPR budget (loads stay in flight across the
// previous chunk's compute) and cuts W-lo L1/L2 demand 8x. A-frags from the
// per-XCD L2 replica batched into regs per chunk. Flag barriers unchanged.
// ---------------------------------------------------------------------------

namespace {
constexpr int NBLK = 256, THREADS = 512;
constexpr int KT0B = 40;           // L0 k-tiles of 32 (K=1280): 8 X + 32 D
constexpr int KT1B = 64;           // L1 k-tiles of 32 (K=2048): 32 D + 32 H1
constexpr int NPH = 513;
constexpr int HP = 128 * 1024;     // u16 elems per h plane
constexpr int SPIN_CAP = 2000000;
// flag slots (u32 index into ctr[1024], all zeroed per launch)
constexpr int F_CREG = 0;          // 8 x 16 (boot atomics)
constexpr int F_BOOT = 128;
constexpr int F_ARR  = 256;        // 256 contiguous
constexpr int F_GO   = 520;
constexpr int F_XARR = 576;        // 8 x 32
}

typedef __bf16 bf16x8 __attribute__((ext_vector_type(8)));
typedef float f32x4 __attribute__((ext_vector_type(4)));
typedef unsigned u32x4 __attribute__((ext_vector_type(4)));

__host__ __device__ __forceinline__ int fswz(int kk) {   // frag order within 32
  return ((kk & 15) >> 2) * 8 + (kk >> 4) * 4 + (kk & 3);
}

__device__ __forceinline__ unsigned short f2bf(float f) {
  unsigned u = __float_as_uint(f);
  u += 0x7fffu + ((u >> 16) & 1u);
  return (unsigned short)(u >> 16);
}
__device__ __forceinline__ float bf2f(unsigned short h) {
  return __uint_as_float(((unsigned)h) << 16);
}
__device__ __forceinline__ float sigm(float x) { return 1.0f / (1.0f + __expf(-x)); }
__device__ __forceinline__ float tanh_f(float x) {
  float e = __expf(-2.0f * fabsf(x));
  float r = (1.0f - e) / (1.0f + e);
  return x >= 0.0f ? r : -r;
}

// ---- LLC-coherent ops (bypass L1+L2) --------------------------------------
__device__ __forceinline__ int load_i32_llc(const int* p) {
  int v;
  asm volatile("global_load_dword %0, %1, off sc0 sc1\n\ts_waitcnt vmcnt(0)"
               : "=v"(v) : "v"(p) : "memory");
  return v;
}
__device__ __forceinline__ uint4 llc_load_issue(const unsigned* p) {
  uint4 v;
  asm volatile("global_load_dwordx4 %0, %1, off sc0 sc1" : "=v"(v) : "v"(p));
  return v;
}
__device__ __forceinline__ void vm_wait0() {
  asm volatile("s_waitcnt vmcnt(0)" ::: "memory");
  __builtin_amdgcn_sched_barrier(0);
}
__device__ __forceinline__ void store_u32_llc(unsigned* p, unsigned v) {
  asm volatile("global_store_dword %0, %1, off sc0 sc1" :: "v"(p), "v"(v) : "memory");
}
__device__ __forceinline__ void store_u16_llc(unsigned short* p, unsigned short v) {
  asm volatile("global_store_short %0, %1, off sc0 sc1" :: "v"(p), "v"(v) : "memory");
}
__device__ __forceinline__ void inv_l1() {
  asm volatile("buffer_inv" ::: "memory");
}
__device__ __forceinline__ int xcc_id() {
  int x;
  asm("s_getreg_b32 %0, hwreg(HW_REG_XCC_ID)" : "=s"(x));
  return x & 7;
}
__device__ __forceinline__ int spin_ge(int* p, int target) {
  for (int it = 0; it < SPIN_CAP; ++it) {
    if (load_i32_llc(p) >= target) return 1;
    __builtin_amdgcn_s_sleep(1);
  }
  return 0;
}
__device__ __forceinline__ bf16x8 asbf(u32x4 v) { return __builtin_bit_cast(bf16x8, v); }
__device__ __forceinline__ bf16x8 asbf4(uint4 v) { return __builtin_bit_cast(bf16x8, v); }

// async global -> LDS, 16B per lane (dest = uniform base + lane*16)
typedef __attribute__((address_space(1))) void gas_void;
typedef __attribute__((address_space(3))) void las_void;
__device__ __forceinline__ void gll16(const void* g, void* l) {
  __builtin_amdgcn_global_load_lds((gas_void*)g, (las_void*)l, 16, 0, 0);
}

#define MFMA3(acc, ah, al, bh, bl)                                            \
  acc = __builtin_amdgcn_mfma_f32_16x16x32_bf16(ah, bh, acc, 0, 0, 0);        \
  acc = __builtin_amdgcn_mfma_f32_16x16x32_bf16(ah, bl, acc, 0, 0, 0);        \
  acc = __builtin_amdgcn_mfma_f32_16x16x32_bf16(al, bh, acc, 0, 0, 0);

// ======================= prep kernels =====================================

__global__ void prep_sort(const int* __restrict__ lens, int* __restrict__ perm,
                          int* __restrict__ lenS, int* __restrict__ ncnt) {
  __shared__ int k_[128], p_[128];
  const int tid = threadIdx.x;
  if (tid < 128) { k_[tid] = (lens[tid] << 8) | (127 - tid); p_[tid] = tid; }
  __syncthreads();
  for (int ph = 0; ph < 128; ++ph) {
    if (tid < 64) {
      int a = 2 * tid + (ph & 1), b = a + 1;
      if (b < 128 && k_[a] < k_[b]) {
        int tk = k_[a]; k_[a] = k_[b]; k_[b] = tk;
        int tp = p_[a]; p_[a] = p_[b]; p_[b] = tp;
      }
    }
    __syncthreads();
  }
  if (tid < 128) { perm[tid] = p_[tid]; lenS[tid] = k_[tid] >> 8; }
  if (tid < 512) {
    int c = 0;
    for (int i = 0; i < 128; ++i) c += ((k_[i] >> 8) > tid) ? 1 : 0;
    ncnt[tid] = c;
  }
}

// emb planes in fragment-interleaved order
__global__ void prep_emb(const float* __restrict__ emb,
                         unsigned short* __restrict__ ehi,
                         unsigned short* __restrict__ elo) {
  int i = blockIdx.x * 256 + threadIdx.x;   // 32768
  int row = i >> 8, e = i & 255;
  int pos = row * 256 + (e >> 5) * 32 + fswz(e & 31);
  float f = emb[i];
  unsigned short h = f2bf(f);
  ehi[pos] = h;
  elo[pos] = f2bf(f - bf2f(h));
}

// W[k][4096] -> per-block frag slabs: e = (blk*KT + kt)*64 + lane.
// lane: cf = lane&15 = u_local*4 + g ; col = g*1024 + blk*4 + u_local
// elem j: k = kt*32 + ((lane>>4)&3)*4 + (j&3) + 16*(j>>2)
__global__ void prep_wslab(const float* __restrict__ W, uint4* __restrict__ Whi,
                           uint4* __restrict__ Wlo, int KT) {
  int e = blockIdx.x * 256 + threadIdx.x;
  int lane = e & 63;
  int kt = (e >> 6) % KT;
  int blk = e / (64 * KT);
  int cf = lane & 15;
  int g = cf & 3, ul = cf >> 2;
  int col = g * 1024 + blk * 4 + ul;
  int kbase = kt * 32 + ((lane >> 4) & 3) * 4;
  unsigned hi[8], lo[8];
#pragma unroll
  for (int j = 0; j < 8; ++j) {
    int k = kbase + (j & 3) + 16 * (j >> 2);
    float f = W[(size_t)k * 4096 + col];
    unsigned short h = f2bf(f);
    hi[j] = h;
    lo[j] = f2bf(f - bf2f(h));
  }
  uint4 vh, vl;
  vh.x = hi[0] | (hi[1] << 16); vh.y = hi[2] | (hi[3] << 16);
  vh.z = hi[4] | (hi[5] << 16); vh.w = hi[6] | (hi[7] << 16);
  vl.x = lo[0] | (lo[1] << 16); vl.y = lo[2] | (lo[3] << 16);
  vl.z = lo[4] | (lo[5] << 16); vl.w = lo[6] | (lo[7] << 16);
  Whi[e] = vh;
  Wlo[e] = vl;
}

// ======================= persistent kernel =================================

__global__ __launch_bounds__(THREADS, 1) void lstm_persist(
    const int* __restrict__ ib,
    const float* __restrict__ bias0, const float* __restrict__ bias1,
    const uint4* __restrict__ Whi0g, const uint4* __restrict__ Wlo0g,
    const uint4* __restrict__ Whi1g, const uint4* __restrict__ Wlo1g,
    const unsigned short* __restrict__ embHi, const unsigned short* __restrict__ embLo,
    const int* __restrict__ perm, const int* __restrict__ lenS,
    const int* __restrict__ ncnt,
    unsigned short* hg0hi, unsigned short* hg0lo,   // [3][128][1024] frag-order
    unsigned short* hg1hi, unsigned short* hg1lo,
    unsigned short* rep,                            // [8][4][128][1024]
    int* ctr, float* __restrict__ out) {
  const int bid = blockIdx.x;
  const int tid = threadIdx.x;
  const int w = tid >> 6;                 // wave 0..7 -> rows w*16..+15
  const int lane = tid & 63;
  const int lr = lane & 15;
  const int lg4 = ((lane >> 4) & 3) * 4;
  const int slotE = ((lane >> 4) & 3) * 8;  // frag u16 offset within 32-group
  const int arow = w * 16 + lr;           // GEMM A row for this lane
  const int srow = tid >> 2;              // cell row 0..127
  const int cu = tid & 3;                 // cell unit 0..3
  const int ug = bid * 4 + cu;            // global unit
  const int fpos = (ug >> 5) * 32 + fswz(ug & 31);  // frag pos of unit in row
  const int permA = perm[arow];
  const int cperm = perm[srow];
  const int clen = lenS[srow];

  __shared__ uint4 Wh0[KT0B * 64];        // 40 KB  (W0-hi)
  __shared__ uint4 Wh1[KT1B * 64];        // 64 KB  (W1-hi)
  __shared__ __align__(16) u32x4 Wch[2][512];  // 16 KB W-lo chunk double-buffer
  __shared__ float zb[2][128][17];        // 17 KB
  __shared__ int s_x, s_rk, s_R, s_ok;

  // ---- one-time: W-hi slabs -> LDS ----
  {
    const uint4* s0 = Whi0g + (size_t)bid * (KT0B * 64);
    for (int i = tid; i < KT0B * 64; i += THREADS) Wh0[i] = s0[i];
    const uint4* s1 = Whi1g + (size_t)bid * (KT1B * 64);
    for (int i = tid; i < KT1B * 64; i += THREADS) Wh1[i] = s1[i];
  }

  float bz0[4], bz1[4];
#pragma unroll
  for (int g = 0; g < 4; ++g) {
    bz0[g] = bias0[g * 1024 + ug];
    bz1[g] = bias1[g * 1024 + ug];
  }
  float c0r = 0.0f, c1r = 0.0f;           // cell states in registers

  // ---- bootstrap: XCD registration + first global sync (atomics, once) ----
  if (tid == 0) {
    s_ok = 1;
    int x = xcc_id();
    s_x = x;
    s_rk = atomicAdd(&ctr[F_CREG + x * 16], 1);
    vm_wait0();
    atomicAdd(&ctr[F_BOOT], 1);
    if (!spin_ge(&ctr[F_BOOT], NBLK)) s_ok = 0;
    int Rv = 1;
    for (int i = 0; i < 8; ++i) {
      int r = load_i32_llc(&ctr[F_CREG + i * 16]);
      if (i == s_x) Rv = r;
    }
    s_R = Rv;
  }
  __syncthreads();
  const int xcd = s_x, rk = s_rk, R = s_R;
  if (!s_ok) return;

  unsigned short* repB = rep + (size_t)xcd * 4 * HP;
  const unsigned short* A0H = repB + (size_t)arow * 1024;
  const unsigned short* A0L = repB + HP + (size_t)arow * 1024;
  const unsigned short* A1H = repB + 2 * HP + (size_t)arow * 1024;
  const unsigned short* A1L = repB + 3 * HP + (size_t)arow * 1024;

  // distribution role: plane pr, 16B chunk ch (pure linear copy)
  const int pr = tid >> 7;                // 0..3: h0hi,h0lo,h1hi,h1lo
  const int ch = (tid & 127) * 8;         // u16 offset
  const unsigned short* spBase =
      (pr == 0) ? hg0hi : (pr == 1) ? hg0lo : (pr == 2) ? hg1hi : hg1lo;
  unsigned short* dp = repB + pr * HP;

  const u32x4* wl0g = (const u32x4*)(Wlo0g + (size_t)bid * (KT0B * 64));
  const u32x4* wl1g = (const u32x4*)(Wlo1g + (size_t)bid * (KT1B * 64));

  // stage W-lo chunk ci (0=X, 1..8=D, 9..12=H1) into Wch[buf]; 1 gll per wave
  auto stage = [&](int ci, int buf) {
    const u32x4* src;
    if (ci == 0) {
      src = wl0g + w * 64;                              // W0lo kt = w
    } else if (ci <= 8) {
      const int q0 = (ci - 1) * 4;
      src = (w < 4) ? (wl0g + (8 + q0 + w) * 64)        // W0lo kt = 8+q0+i
                    : (wl1g + (q0 + w - 4) * 64);       // W1lo kt = q0+i
    } else {
      const int q0 = (ci - 9) * 8;
      src = wl1g + (32 + q0 + w) * 64;                  // W1lo kt = 32+q0+i
    }
    gll16((const void*)(src + lane), (void*)&Wch[buf][w * 64]);
  };

  for (int p = 0; p < NPH; ++p) {
    const int nact0 = (p < 512) ? ncnt[p] : 0;
    const int nact1 = (p >= 1) ? ncnt[p - 1] : 0;
    const bool doL0 = (p < 512) && (w * 16 < nact0);
    const bool doL1 = (p >= 1) && (w * 16 < nact1);

    f32x4 acc0 = (f32x4){0.f, 0.f, 0.f, 0.f};
    f32x4 acc1 = (f32x4){0.f, 0.f, 0.f, 0.f};

    // ---- (A) dist: issue LLC loads; stage chunk 0 (constant W-lo) ----
    const int ncopy = ncnt[p == 0 ? 0 : p - 1];
    const int par = (pr < 2) ? (p + 2) % 3 : (p + 1) % 3;
    const unsigned short* sp = spBase + (size_t)par * HP;
    uint4 dv0, dv1, dv2, dv3;
    const int dr0 = rk, dr1 = rk + R, dr2 = rk + 2 * R, dr3 = rk + 3 * R;
    if (dr0 < ncopy) dv0 = llc_load_issue((const unsigned*)(sp + dr0 * 1024 + ch));
    if (dr1 < ncopy) dv1 = llc_load_issue((const unsigned*)(sp + dr1 * 1024 + ch));
    if (dr2 < ncopy) dv2 = llc_load_issue((const unsigned*)(sp + dr2 * 1024 + ch));
    if (dr3 < ncopy) dv3 = llc_load_issue((const unsigned*)(sp + dr3 * 1024 + ch));
    stage(0, 0);

    // ---- (B) finish dist: wait + store into replica (plain L2 stores) ----
    vm_wait0();
    if (dr0 < ncopy) *(uint4*)(dp + dr0 * 1024 + ch) = dv0;
    if (dr1 < ncopy) *(uint4*)(dp + dr1 * 1024 + ch) = dv1;
    if (dr2 < ncopy) *(uint4*)(dp + dr2 * 1024 + ch) = dv2;
    if (dr3 < ncopy) *(uint4*)(dp + dr3 * 1024 + ch) = dv3;
    for (int r = rk + 4 * R; r < ncopy; r += R) {     // safety (R<32 only)
      uint4 v = llc_load_issue((const unsigned*)(sp + r * 1024 + ch));
      vm_wait0();
      *(uint4*)(dp + r * 1024 + ch) = v;
    }
    __syncthreads();                      // drains stores + chunk-0 gll

    // ---- (C) XCD barrier: 1 round (all blocks poll all arrive flags) ----
    if (tid == 0) store_u32_llc((unsigned*)&ctr[F_XARR + xcd * 32 + rk], p + 1);
    if (tid < 32 && tid < R) {
      if (!spin_ge(&ctr[F_XARR + xcd * 32 + tid], p + 1)) s_ok = 0;
    }
    __syncthreads();
    if (!s_ok) break;
    inv_l1();                             // fresh L1 view of replica

    // ---- (D) chunk-pipelined GEMM: X (ci 0) ----
    {
      stage(1, 1);
      if (doL0) {
        const int tok = ib[(size_t)permA * 512 + p];
        const unsigned short* eh = embHi + tok * 256;
        const unsigned short* el = embLo + tok * 256;
        u32x4 aH[8], aL[8];
#pragma unroll
        for (int kt = 0; kt < 8; ++kt) {
          aH[kt] = *(const u32x4*)(eh + kt * 32 + slotE);
          aL[kt] = *(const u32x4*)(el + kt * 32 + slotE);
        }
#pragma unroll
        for (int kt = 0; kt < 8; ++kt) {
          MFMA3(acc0, asbf(aH[kt]), asbf(aL[kt]),
                asbf4(Wh0[kt * 64 + lane]), asbf(Wch[0][kt * 64 + lane]))
        }
      }
      __syncthreads();
    }
    // ---- D region (ci 1..8): L0 kt 8+q / L1 kt q, q = q0..q0+3 ----
#pragma unroll 1
    for (int ci = 1; ci <= 8; ++ci) {
      stage(ci + 1, (ci + 1) & 1);
      const int q0 = (ci - 1) * 4;
      const int buf = ci & 1;
      if (doL0 || doL1) {
        u32x4 aH[4], aL[4];
#pragma unroll
        for (int i = 0; i < 4; ++i) {
          aH[i] = *(const u32x4*)(A0H + (q0 + i) * 32 + slotE);
          aL[i] = *(const u32x4*)(A0L + (q0 + i) * 32 + slotE);
        }
#pragma unroll
        for (int i = 0; i < 4; ++i) {
          const bf16x8 ah = asbf(aH[i]), al = asbf(aL[i]);
          if (doL0) {
            MFMA3(acc0, ah, al, asbf4(Wh0[(8 + q0 + i) * 64 + lane]),
                  asbf(Wch[buf][i * 64 + lane]))
          }
          if (doL1) {
            MFMA3(acc1, ah, al, asbf4(Wh1[(q0 + i) * 64 + lane]),
                  asbf(Wch[buf][(4 + i) * 64 + lane]))
          }
        }
      }
      __syncthreads();
    }
    // ---- H1 region (ci 9..12): L1 kt 32+q, q = q0..q0+7 ----
#pragma unroll 1
    for (int ci = 9; ci <= 12; ++ci) {
      if (ci < 12) stage(ci + 1, (ci + 1) & 1);
      const int q0 = (ci - 9) * 8;
      const int buf = ci & 1;
      if (doL1) {
        u32x4 aH[8], aL[8];
#pragma unroll
        for (int i = 0; i < 8; ++i) {
          aH[i] = *(const u32x4*)(A1H + (q0 + i) * 32 + slotE);
          aL[i] = *(const u32x4*)(A1L + (q0 + i) * 32 + slotE);
        }
#pragma unroll
        for (int i = 0; i < 8; ++i) {
          MFMA3(acc1, asbf(aH[i]), asbf(aL[i]),
                asbf4(Wh1[(32 + q0 + i) * 64 + lane]),
                asbf(Wch[buf][i * 64 + lane]))
        }
      }
      __syncthreads();
    }

    // ---- (E) z exchange (C/D: row = 4*(l>>4)+reg, col = l&15) ----
    if (doL0) {
#pragma unroll
      for (int rr = 0; rr < 4; ++rr) zb[0][w * 16 + lg4 + rr][lr] = acc0[rr];
    }
    if (doL1) {
#pragma unroll
      for (int rr = 0; rr < 4; ++rr) zb[1][w * 16 + lg4 + rr][lr] = acc1[rr];
    }
    __syncthreads();

    // ---- (F) fused cells (thread = row x unit), frag-order h stores ----
    if (p < 512 && p < clen) {            // L0, t = p
      const float zi = zb[0][srow][cu * 4 + 0] + bz0[0];
      const float zj = zb[0][srow][cu * 4 + 1] + bz0[1];
      const float zf = zb[0][srow][cu * 4 + 2] + bz0[2];
      const float zo = zb[0][srow][cu * 4 + 3] + bz0[3];
      const float nc = c0r * sigm(zf + 1.0f) + sigm(zi) * tanh_f(zj);
      const float nh = tanh_f(nc) * sigm(zo);
      c0r = nc;
      const unsigned short hh = f2bf(nh);
      const unsigned short hl = f2bf(nh - bf2f(hh));
      const size_t idx = (size_t)(p % 3) * HP + srow * 1024 + fpos;
      store_u16_llc(&hg0hi[idx], hh);
      store_u16_llc(&hg0lo[idx], hl);
    }
    if (p >= 1 && (p - 1) < clen) {       // L1, t = p-1
      const float zi = zb[1][srow][cu * 4 + 0] + bz1[0];
      const float zj = zb[1][srow][cu * 4 + 1] + bz1[1];
      const float zf = zb[1][srow][cu * 4 + 2] + bz1[2];
      const float zo = zb[1][srow][cu * 4 + 3] + bz1[3];
      const float nc = c1r * sigm(zf + 1.0f) + sigm(zi) * tanh_f(zj);
      const float nh = tanh_f(nc) * sigm(zo);
      c1r = nc;
      const unsigned short hh = f2bf(nh);
      const unsigned short hl = f2bf(nh - bf2f(hh));
      const size_t idx = (size_t)((p + 2) % 3) * HP + srow * 1024 + fpos;
      store_u16_llc(&hg1hi[idx], hh);
      store_u16_llc(&hg1lo[idx], hl);
      if (p - 1 == clen - 1) out[(size_t)cperm * 1024 + ug] = nh;
    }

    // ---- (G) global barrier (flag-based, leader + GO) ----
    vm_wait0();                           // h stores LLC-visible
    __syncthreads();
    if (tid == 0) store_u32_llc((unsigned*)&ctr[F_ARR + bid], p + 1);
    if (bid == 0) {
      if (tid < 256) {
        if (!spin_ge(&ctr[F_ARR + tid], p + 1)) s_ok = 0;
      }
      __syncthreads();
      if (tid == 0) store_u32_llc((unsigned*)&ctr[F_GO], p + 1);
    }
    if (tid == 0) {
      if (!spin_ge(&ctr[F_GO], p + 1)) s_ok = 0;
    }
    __syncthreads();
    if (!s_ok) break;
  }
}

// ======================= host launch =======================================

extern "C" void kernel_launch(void* const* d_in, const int* in_sizes, int n_in,
                              void* d_out, int out_size, void* d_ws, size_t ws_size,
                              hipStream_t stream) {
  const int*   ib   = (const int*)d_in[0];
  const int*   lens = (const int*)d_in[1];
  const float* emb  = (const float*)d_in[2];
  const float* W0   = (const float*)d_in[3];
  const float* b0   = (const float*)d_in[4];
  const float* W1   = (const float*)d_in[5];
  const float* b1   = (const float*)d_in[6];
  (void)in_sizes; (void)n_in; (void)out_size; (void)ws_size;

  char* ws = (char*)d_ws;
  size_t off = 0;
  auto alloc = [&](size_t bytes) { char* q = ws + off; off += (bytes + 255) & ~(size_t)255; return q; };

  int*            ctr   = (int*)alloc(4096);
  unsigned short* hg0hi = (unsigned short*)alloc((size_t)3 * HP * 2);
  unsigned short* hg0lo = (unsigned short*)alloc((size_t)3 * HP * 2);
  unsigned short* hg1hi = (unsigned short*)alloc((size_t)3 * HP * 2);
  unsigned short* hg1lo = (unsigned short*)alloc((size_t)3 * HP * 2);
  const size_t zero_bytes = off;          // ctr + h planes
  unsigned short* embHi = (unsigned short*)alloc(128 * 256 * 2);
  unsigned short* embLo = (unsigned short*)alloc(128 * 256 * 2);
  int*            perm  = (int*)alloc(4096);   // perm[128], lenS[128], ncnt[512]
  int*            lenS  = perm + 128;
  int*            ncnt  = perm + 256;
  unsigned short* rep   = (unsigned short*)alloc((size_t)8 * 4 * HP * 2);
  uint4*          Whi0  = (uint4*)alloc((size_t)NBLK * KT0B * 64 * 16);
  uint4*          Wlo0  = (uint4*)alloc((size_t)NBLK * KT0B * 64 * 16);
  uint4*          Whi1  = (uint4*)alloc((size_t)NBLK * KT1B * 64 * 16);
  uint4*          Wlo1  = (uint4*)alloc((size_t)NBLK * KT1B * 64 * 16);

  hipMemsetAsync(d_ws, 0, zero_bytes, stream);
  prep_sort<<<1, 512, 0, stream>>>(lens, perm, lenS, ncnt);
  prep_emb<<<128, 256, 0, stream>>>(emb, embHi, embLo);
  prep_wslab<<<(NBLK * KT0B * 64) / 256, 256, 0, stream>>>(W0, Whi0, Wlo0, KT0B);
  prep_wslab<<<(NBLK * KT1B * 64) / 256, 256, 0, stream>>>(W1, Whi1, Wlo1, KT1B);
  lstm_persist<<<NBLK, THREADS, 0, stream>>>(
      ib, b0, b1, Whi0, Wlo0, Whi1, Wlo1, embHi, embLo,
      perm, lenS, ncnt, hg0hi, hg0lo, hg1hi, hg1lo, rep, ctr, (float*)d_out);
}

// Round 10
// 16334.233 us; speedup vs baseline: 1.8453x; 1.0527x over previous
//
#include <hip/hip_runtime.h>

// ---------------------------------------------------------------------------
// 2-layer LSTM encoder, B=128 T=512 E=256 H=1024 (round 10).
// Persistent kernel: 256 blocks x 512 threads (8 waves, fused dual-layer).
// Per phase p: L0 (t=p): z0=[x_p;h0(p-1)]@W0 -> h0(p)
//             L1 (t=p-1): z1=[h0(p-1);h1(p-2)]@W1 -> h1(p-1)
// Split-bf16 x3 MFMA (verified r1-r8). W-hi LDS-resident (W1 kt56..63
// streamed in chunk C4). W-lo staged via async global_load_lds in 5 BIG
// chunks (24KB, dbuf, stage-1-ahead) so chunk compute > gll latency.
// r10 fix: ALL flag signaling back to LLC (sc0 sc1) — r9's sc0-only flags
// deadlocked (L1-stale polls -> SPIN_CAP -> early exit -> zero output).
// XCD arrive region widened to stride 64 (guards rk>=32 overflow).
// LDS trimmed to 156.2 KB (headroom vs r9's 160.3).
// ---------------------------------------------------------------------------

namespace {
constexpr int NBLK = 256, THREADS = 512;
constexpr int KT0B = 40;           // L0 k-tiles of 32 (K=1280): 8 X + 32 D
constexpr int KT1B = 64;           // L1 k-tiles of 32 (K=2048): 32 D + 32 H1
constexpr int WH1KT = 56;          // W1-hi kt resident in LDS (56..63 streamed)
constexpr int NPH = 513;
constexpr int HP = 128 * 1024;     // u16 elems per h plane
constexpr int SPIN_CAP = 2000000;
// flag slots (u32 index into ctr[2048], zeroed per launch) — ALL LLC
constexpr int F_CREG = 0;          // 8 x 16 (boot atomics)
constexpr int F_BOOT = 128;
constexpr int F_ARR  = 256;        // 256 contiguous (global arrive)
constexpr int F_GO   = 520;
constexpr int F_XARR = 576;        // 8 x 64 (mid-phase XCD arrive)
constexpr int kNSLAB[5] = {24, 24, 24, 16, 24};
}

typedef __bf16 bf16x8 __attribute__((ext_vector_type(8)));
typedef float f32x4 __attribute__((ext_vector_type(4)));
typedef unsigned u32x4 __attribute__((ext_vector_type(4)));

__host__ __device__ __forceinline__ int fswz(int kk) {   // frag order within 32
  return ((kk & 15) >> 2) * 8 + (kk >> 4) * 4 + (kk & 3);
}

__device__ __forceinline__ unsigned short f2bf(float f) {
  unsigned u = __float_as_uint(f);
  u += 0x7fffu + ((u >> 16) & 1u);
  return (unsigned short)(u >> 16);
}
__device__ __forceinline__ float bf2f(unsigned short h) {
  return __uint_as_float(((unsigned)h) << 16);
}
__device__ __forceinline__ float sigm(float x) { return 1.0f / (1.0f + __expf(-x)); }
__device__ __forceinline__ float tanh_f(float x) {
  float e = __expf(-2.0f * fabsf(x));
  float r = (1.0f - e) / (1.0f + e);
  return x >= 0.0f ? r : -r;
}

// ---- LLC-coherent ops (bypass L1+L2) --------------------------------------
__device__ __forceinline__ int load_i32_llc(const int* p) {
  int v;
  asm volatile("global_load_dword %0, %1, off sc0 sc1\n\ts_waitcnt vmcnt(0)"
               : "=v"(v) : "v"(p) : "memory");
  return v;
}
__device__ __forceinline__ uint4 llc_load_issue(const unsigned* p) {
  uint4 v;
  asm volatile("global_load_dwordx4 %0, %1, off sc0 sc1" : "=v"(v) : "v"(p));
  return v;
}
__device__ __forceinline__ void vm_wait0() {
  asm volatile("s_waitcnt vmcnt(0)" ::: "memory");
  __builtin_amdgcn_sched_barrier(0);
}
__device__ __forceinline__ void store_u32_llc(unsigned* p, unsigned v) {
  asm volatile("global_store_dword %0, %1, off sc0 sc1" :: "v"(p), "v"(v) : "memory");
}
__device__ __forceinline__ void store_u16_llc(unsigned short* p, unsigned short v) {
  asm volatile("global_store_short %0, %1, off sc0 sc1" :: "v"(p), "v"(v) : "memory");
}
__device__ __forceinline__ void inv_l1() {
  asm volatile("buffer_inv" ::: "memory");
}
__device__ __forceinline__ int xcc_id() {
  int x;
  asm("s_getreg_b32 %0, hwreg(HW_REG_XCC_ID)" : "=s"(x));
  return x & 7;
}
__device__ __forceinline__ int spin_ge(int* p, int target) {
  for (int it = 0; it < SPIN_CAP; ++it) {
    if (load_i32_llc(p) >= target) return 1;
    __builtin_amdgcn_s_sleep(1);
  }
  return 0;
}
__device__ __forceinline__ bf16x8 asbf(u32x4 v) { return __builtin_bit_cast(bf16x8, v); }
__device__ __forceinline__ bf16x8 asbf4(uint4 v) { return __builtin_bit_cast(bf16x8, v); }

// async global -> LDS, 16B per lane (dest = wave-uniform base + lane*16)
typedef __attribute__((address_space(1))) void gas_void;
typedef __attribute__((address_space(3))) void las_void;
__device__ __forceinline__ void gll16(const void* g, void* l) {
  __builtin_amdgcn_global_load_lds((gas_void*)g, (las_void*)l, 16, 0, 0);
}

#define MFMA3(acc, ah, al, bh, bl)                                            \
  acc = __builtin_amdgcn_mfma_f32_16x16x32_bf16(ah, bh, acc, 0, 0, 0);        \
  acc = __builtin_amdgcn_mfma_f32_16x16x32_bf16(ah, bl, acc, 0, 0, 0);        \
  acc = __builtin_amdgcn_mfma_f32_16x16x32_bf16(al, bh, acc, 0, 0, 0);

// ======================= prep kernels =====================================

__global__ void prep_sort(const int* __restrict__ lens, int* __restrict__ perm,
                          int* __restrict__ lenS, int* __restrict__ ncnt) {
  __shared__ int k_[128], p_[128];
  const int tid = threadIdx.x;
  if (tid < 128) { k_[tid] = (lens[tid] << 8) | (127 - tid); p_[tid] = tid; }
  __syncthreads();
  for (int ph = 0; ph < 128; ++ph) {
    if (tid < 64) {
      int a = 2 * tid + (ph & 1), b = a + 1;
      if (b < 128 && k_[a] < k_[b]) {
        int tk = k_[a]; k_[a] = k_[b]; k_[b] = tk;
        int tp = p_[a]; p_[a] = p_[b]; p_[b] = tp;
      }
    }
    __syncthreads();
  }
  if (tid < 128) { perm[tid] = p_[tid]; lenS[tid] = k_[tid] >> 8; }
  if (tid < 512) {
    int c = 0;
    for (int i = 0; i < 128; ++i) c += ((k_[i] >> 8) > tid) ? 1 : 0;
    ncnt[tid] = c;
  }
}

__global__ void prep_emb(const float* __restrict__ emb,
                         unsigned short* __restrict__ ehi,
                         unsigned short* __restrict__ elo) {
  int i = blockIdx.x * 256 + threadIdx.x;   // 32768
  int row = i >> 8, e = i & 255;
  int pos = row * 256 + (e >> 5) * 32 + fswz(e & 31);
  float f = emb[i];
  unsigned short h = f2bf(f);
  ehi[pos] = h;
  elo[pos] = f2bf(f - bf2f(h));
}

// W[k][4096] -> per-block frag slabs: e = (blk*KT + kt)*64 + lane.
__global__ void prep_wslab(const float* __restrict__ W, uint4* __restrict__ Whi,
                           uint4* __restrict__ Wlo, int KT) {
  int e = blockIdx.x * 256 + threadIdx.x;
  int lane = e & 63;
  int kt = (e >> 6) % KT;
  int blk = e / (64 * KT);
  int cf = lane & 15;
  int g = cf & 3, ul = cf >> 2;
  int col = g * 1024 + blk * 4 + ul;
  int kbase = kt * 32 + ((lane >> 4) & 3) * 4;
  unsigned hi[8], lo[8];
#pragma unroll
  for (int j = 0; j < 8; ++j) {
    int k = kbase + (j & 3) + 16 * (j >> 2);
    float f = W[(size_t)k * 4096 + col];
    unsigned short h = f2bf(f);
    hi[j] = h;
    lo[j] = f2bf(f - bf2f(h));
  }
  uint4 vh, vl;
  vh.x = hi[0] | (hi[1] << 16); vh.y = hi[2] | (hi[3] << 16);
  vh.z = hi[4] | (hi[5] << 16); vh.w = hi[6] | (hi[7] << 16);
  vl.x = lo[0] | (lo[1] << 16); vl.y = lo[2] | (lo[3] << 16);
  vl.z = lo[4] | (lo[5] << 16); vl.w = lo[6] | (lo[7] << 16);
  Whi[e] = vh;
  Wlo[e] = vl;
}

// ======================= persistent kernel =================================

__global__ __launch_bounds__(THREADS, 1) void lstm_persist(
    const int* __restrict__ ib,
    const float* __restrict__ bias0, const float* __restrict__ bias1,
    const uint4* __restrict__ Whi0g, const uint4* __restrict__ Wlo0g,
    const uint4* __restrict__ Whi1g, const uint4* __restrict__ Wlo1g,
    const unsigned short* __restrict__ embHi, const unsigned short* __restrict__ embLo,
    const int* __restrict__ perm, const int* __restrict__ lenS,
    const int* __restrict__ ncnt,
    unsigned short* hg0hi, unsigned short* hg0lo,   // [3][128][1024] frag-order
    unsigned short* hg1hi, unsigned short* hg1lo,
    unsigned short* rep,                            // [8][4][128][1024]
    int* ctr, float* __restrict__ out) {
  const int bid = blockIdx.x;
  const int tid = threadIdx.x;
  const int w = tid >> 6;                 // wave 0..7 -> rows w*16..+15
  const int lane = tid & 63;
  const int lr = lane & 15;
  const int lg4 = ((lane >> 4) & 3) * 4;
  const int slotE = ((lane >> 4) & 3) * 8;  // frag u16 offset within 32-group
  const int arow = w * 16 + lr;           // GEMM A row for this lane
  const int srow = tid >> 2;              // cell row 0..127
  const int cu = tid & 3;                 // cell unit 0..3
  const int ug = bid * 4 + cu;            // global unit
  const int fpos = (ug >> 5) * 32 + fswz(ug & 31);
  const int permA = perm[arow];
  const int cperm = perm[srow];
  const int clen = lenS[srow];

  __shared__ uint4 Wh0[KT0B * 64];              // 40 KB
  __shared__ uint4 Wh1[WH1KT * 64];             // 56 KB
  __shared__ __align__(16) u32x4 Wch[2][24 * 64];  // 48 KB (2 x 24KB chunks)
  __shared__ float zb[128][17];                 // 8.5 KB (reused L0 then L1)
  __shared__ int s_x, s_rk, s_R, s_ok;

  // ---- one-time: W-hi slabs -> LDS ----
  {
    const uint4* s0 = Whi0g + (size_t)bid * (KT0B * 64);
    for (int i = tid; i < KT0B * 64; i += THREADS) Wh0[i] = s0[i];
    const uint4* s1 = Whi1g + (size_t)bid * (KT1B * 64);
    for (int i = tid; i < WH1KT * 64; i += THREADS) Wh1[i] = s1[i];
  }

  float bz0[4], bz1[4];
#pragma unroll
  for (int g = 0; g < 4; ++g) {
    bz0[g] = bias0[g * 1024 + ug];
    bz1[g] = bias1[g * 1024 + ug];
  }
  float c0r = 0.0f, c1r = 0.0f;

  // ---- bootstrap (LLC atomics, once) ----
  if (tid == 0) {
    s_ok = 1;
    int x = xcc_id();
    s_x = x;
    s_rk = atomicAdd(&ctr[F_CREG + x * 16], 1);
    vm_wait0();
    atomicAdd(&ctr[F_BOOT], 1);
    if (!spin_ge(&ctr[F_BOOT], NBLK)) s_ok = 0;
    int Rv = 1;
    for (int i = 0; i < 8; ++i) {
      int r = load_i32_llc(&ctr[F_CREG + i * 16]);
      if (i == s_x) Rv = r;
    }
    s_R = Rv;
  }
  __syncthreads();
  const int xcd = s_x, rk = s_rk, R = s_R;
  if (!s_ok) return;

  unsigned short* repB = rep + (size_t)xcd * 4 * HP;
  const unsigned short* A0H = repB + (size_t)arow * 1024;
  const unsigned short* A0L = repB + HP + (size_t)arow * 1024;
  const unsigned short* A1H = repB + 2 * HP + (size_t)arow * 1024;
  const unsigned short* A1L = repB + 3 * HP + (size_t)arow * 1024;

  // distribution role: plane pr, 16B chunk ch
  const int pr = tid >> 7;
  const int ch = (tid & 127) * 8;
  const unsigned short* spBase =
      (pr == 0) ? hg0hi : (pr == 1) ? hg0lo : (pr == 2) ? hg1hi : hg1lo;
  unsigned short* dp = repB + pr * HP;

  const u32x4* wl0g = (const u32x4*)(Wlo0g + (size_t)bid * (KT0B * 64));
  const u32x4* wl1g = (const u32x4*)(Wlo1g + (size_t)bid * (KT1B * 64));
  const u32x4* wh1g = (const u32x4*)(Whi1g + (size_t)bid * (KT1B * 64));

  // slab source for chunk c, slab s
  auto slabSrc = [&](int c, int s) -> const u32x4* {
    if (c == 0) return (s < 16) ? wl0g + s * 64 : wl1g + (s - 16) * 64;
    if (c == 1) return (s < 12) ? wl0g + (16 + s) * 64 : wl1g + (s - 4) * 64;
    if (c == 2) return (s < 12) ? wl0g + (28 + s) * 64 : wl1g + (8 + s) * 64;
    if (c == 3) return wl1g + (32 + s) * 64;
    return (s < 16) ? wl1g + (48 + s) * 64 : wh1g + (40 + s) * 64;  // kt56..63
  };
  auto stageChunk = [&](int c, int buf) {
    const int n = kNSLAB[c];
    for (int s = w; s < n; s += 8)
      gll16((const void*)(slabSrc(c, s) + lane), (void*)&Wch[buf][s * 64]);
  };

  // prologue: stage C0 (buf0), C1 (buf1) of phase 0
  stageChunk(0, 0);
  stageChunk(1, 1);

  for (int p = 0; p < NPH; ++p) {
    const int nact0 = (p < 512) ? ncnt[p] : 0;
    const int nact1 = (p >= 1) ? ncnt[p - 1] : 0;
    const bool doL0 = (p < 512) && (w * 16 < nact0);
    const bool doL1 = (p >= 1) && (w * 16 < nact1);

    f32x4 acc0 = (f32x4){0.f, 0.f, 0.f, 0.f};
    f32x4 acc1 = (f32x4){0.f, 0.f, 0.f, 0.f};

    // ---- (A) dist: issue LLC loads, wait, store into replica ----
    {
      const int ncopy = ncnt[p == 0 ? 0 : p - 1];
      const int par = (pr < 2) ? (p + 2) % 3 : (p + 1) % 3;
      const unsigned short* sp = spBase + (size_t)par * HP;
      uint4 dv0, dv1, dv2, dv3;
      const int dr0 = rk, dr1 = rk + R, dr2 = rk + 2 * R, dr3 = rk + 3 * R;
      if (dr0 < ncopy) dv0 = llc_load_issue((const unsigned*)(sp + dr0 * 1024 + ch));
      if (dr1 < ncopy) dv1 = llc_load_issue((const unsigned*)(sp + dr1 * 1024 + ch));
      if (dr2 < ncopy) dv2 = llc_load_issue((const unsigned*)(sp + dr2 * 1024 + ch));
      if (dr3 < ncopy) dv3 = llc_load_issue((const unsigned*)(sp + dr3 * 1024 + ch));
      vm_wait0();
      if (dr0 < ncopy) *(uint4*)(dp + dr0 * 1024 + ch) = dv0;
      if (dr1 < ncopy) *(uint4*)(dp + dr1 * 1024 + ch) = dv1;
      if (dr2 < ncopy) *(uint4*)(dp + dr2 * 1024 + ch) = dv2;
      if (dr3 < ncopy) *(uint4*)(dp + dr3 * 1024 + ch) = dv3;
      for (int r = rk + 4 * R; r < ncopy; r += R) {
        uint4 v = llc_load_issue((const unsigned*)(sp + r * 1024 + ch));
        vm_wait0();
        *(uint4*)(dp + r * 1024 + ch) = v;
      }
    }
    __syncthreads();                      // dist stores drained (vmcnt(0))

    // ---- (B) XCD barrier (LLC flags, stride-64 region) ----
    if (tid == 0) store_u32_llc((unsigned*)&ctr[F_XARR + xcd * 64 + rk], p + 1);
    if (tid < 64 && tid < R) {
      if (!spin_ge(&ctr[F_XARR + xcd * 64 + tid], p + 1)) s_ok = 0;
    }
    __syncthreads();
    if (!s_ok) break;
    inv_l1();                             // fresh L1 view of replica

    // ---- (C) 5-chunk GEMM, stage-1-ahead ----
    // C0 (buf0): X + D q0..7 (L0) ; D q0..7 (L1)
    {
      if (doL0) {
        const int tok = ib[(size_t)permA * 512 + p];
        const unsigned short* eh = embHi + tok * 256;
        const unsigned short* el = embLo + tok * 256;
#pragma unroll
        for (int kt = 0; kt < 8; ++kt) {
          const bf16x8 ah = asbf(*(const u32x4*)(eh + kt * 32 + slotE));
          const bf16x8 al = asbf(*(const u32x4*)(el + kt * 32 + slotE));
          MFMA3(acc0, ah, al, asbf4(Wh0[kt * 64 + lane]), asbf(Wch[0][kt * 64 + lane]))
        }
      }
      if (doL0 || doL1) {
#pragma unroll
        for (int q = 0; q < 8; ++q) {
          const bf16x8 ah = asbf(*(const u32x4*)(A0H + q * 32 + slotE));
          const bf16x8 al = asbf(*(const u32x4*)(A0L + q * 32 + slotE));
          if (doL0) {
            MFMA3(acc0, ah, al, asbf4(Wh0[(8 + q) * 64 + lane]),
                  asbf(Wch[0][(8 + q) * 64 + lane]))
          }
          if (doL1) {
            MFMA3(acc1, ah, al, asbf4(Wh1[q * 64 + lane]),
                  asbf(Wch[0][(16 + q) * 64 + lane]))
          }
        }
      }
      __syncthreads();
    }
    // C1 (buf1): D q8..19 ; stage C2 -> buf0
    {
      stageChunk(2, 0);
      if (doL0 || doL1) {
#pragma unroll
        for (int qq = 0; qq < 12; ++qq) {
          const int q = 8 + qq;
          const bf16x8 ah = asbf(*(const u32x4*)(A0H + q * 32 + slotE));
          const bf16x8 al = asbf(*(const u32x4*)(A0L + q * 32 + slotE));
          if (doL0) {
            MFMA3(acc0, ah, al, asbf4(Wh0[(8 + q) * 64 + lane]),
                  asbf(Wch[1][qq * 64 + lane]))
          }
          if (doL1) {
            MFMA3(acc1, ah, al, asbf4(Wh1[q * 64 + lane]),
                  asbf(Wch[1][(12 + qq) * 64 + lane]))
          }
        }
      }
      __syncthreads();
    }
    // C2 (buf0): D q20..31 ; stage C3 -> buf1
    {
      stageChunk(3, 1);
      if (doL0 || doL1) {
#pragma unroll
        for (int qq = 0; qq < 12; ++qq) {
          const int q = 20 + qq;
          const bf16x8 ah = asbf(*(const u32x4*)(A0H + q * 32 + slotE));
          const bf16x8 al = asbf(*(const u32x4*)(A0L + q * 32 + slotE));
          if (doL0) {
            MFMA3(acc0, ah, al, asbf4(Wh0[(8 + q) * 64 + lane]),
                  asbf(Wch[0][qq * 64 + lane]))
          }
          if (doL1) {
            MFMA3(acc1, ah, al, asbf4(Wh1[q * 64 + lane]),
                  asbf(Wch[0][(12 + qq) * 64 + lane]))
          }
        }
      }
      __syncthreads();
    }
    // C3 (buf1): H1 q0..15 ; stage C4 -> buf0
    {
      stageChunk(4, 0);
      if (doL1) {
#pragma unroll
        for (int q = 0; q < 16; ++q) {
          const bf16x8 ah = asbf(*(const u32x4*)(A1H + q * 32 + slotE));
          const bf16x8 al = asbf(*(const u32x4*)(A1L + q * 32 + slotE));
          MFMA3(acc1, ah, al, asbf4(Wh1[(32 + q) * 64 + lane]),
                asbf(Wch[1][q * 64 + lane]))
        }
      }
      __syncthreads();
    }
    // C4 (buf0): H1 q16..31 (W1-hi kt56..63 streamed at slabs 16..23)
    {
      if (doL1) {
#pragma unroll
        for (int q = 16; q < 32; ++q) {
          const bf16x8 ah = asbf(*(const u32x4*)(A1H + q * 32 + slotE));
          const bf16x8 al = asbf(*(const u32x4*)(A1L + q * 32 + slotE));
          const bf16x8 bl = asbf(Wch[0][(q - 16) * 64 + lane]);
          bf16x8 bh;
          if (q < 24) bh = asbf4(Wh1[(32 + q) * 64 + lane]);
          else        bh = asbf(Wch[0][(16 + q - 24) * 64 + lane]);
          MFMA3(acc1, ah, al, bh, bl)
        }
      }
      __syncthreads();
    }

    // ---- (D) stage next phase C0/C1 (constant data; lands during tail) ----
    if (p + 1 < NPH) {
      stageChunk(0, 0);
      stageChunk(1, 1);
    }

    // ---- (E) z exchange (zb reused) + cells ----
    if (doL0) {
#pragma unroll
      for (int rr = 0; rr < 4; ++rr) zb[w * 16 + lg4 + rr][lr] = acc0[rr];
    }
    __syncthreads();
    const bool act0 = (p < 512) && (p < clen);
    float z0i = 0, z0j = 0, z0f = 0, z0o = 0;
    if (act0) {
      z0i = zb[srow][cu * 4 + 0] + bz0[0];
      z0j = zb[srow][cu * 4 + 1] + bz0[1];
      z0f = zb[srow][cu * 4 + 2] + bz0[2];
      z0o = zb[srow][cu * 4 + 3] + bz0[3];
    }
    __syncthreads();
    if (doL1) {
#pragma unroll
      for (int rr = 0; rr < 4; ++rr) zb[w * 16 + lg4 + rr][lr] = acc1[rr];
    }
    if (act0) {                           // L0 cell overlaps L1 z-exchange
      const float nc = c0r * sigm(z0f + 1.0f) + sigm(z0i) * tanh_f(z0j);
      const float nh = tanh_f(nc) * sigm(z0o);
      c0r = nc;
      const unsigned short hh = f2bf(nh);
      const unsigned short hl = f2bf(nh - bf2f(hh));
      const size_t idx = (size_t)(p % 3) * HP + srow * 1024 + fpos;
      store_u16_llc(&hg0hi[idx], hh);
      store_u16_llc(&hg0lo[idx], hl);
    }
    __syncthreads();
    if (p >= 1 && (p - 1) < clen) {       // L1 cell, t = p-1
      const float z1i = zb[srow][cu * 4 + 0] + bz1[0];
      const float z1j = zb[srow][cu * 4 + 1] + bz1[1];
      const float z1f = zb[srow][cu * 4 + 2] + bz1[2];
      const float z1o = zb[srow][cu * 4 + 3] + bz1[3];
      const float nc = c1r * sigm(z1f + 1.0f) + sigm(z1i) * tanh_f(z1j);
      const float nh = tanh_f(nc) * sigm(z1o);
      c1r = nc;
      const unsigned short hh = f2bf(nh);
      const unsigned short hl = f2bf(nh - bf2f(hh));
      const size_t idx = (size_t)((p + 2) % 3) * HP + srow * 1024 + fpos;
      store_u16_llc(&hg1hi[idx], hh);
      store_u16_llc(&hg1lo[idx], hl);
      if (p - 1 == clen - 1) out[(size_t)cperm * 1024 + ug] = nh;
    }

    // ---- (F) global barrier (LLC flags, r8-proven pattern) ----
    vm_wait0();                           // h stores LLC-visible
    __syncthreads();
    if (tid == 0) store_u32_llc((unsigned*)&ctr[F_ARR + bid], p + 1);
    if (bid == 0) {
      if (tid < 256) {
        if (!spin_ge(&ctr[F_ARR + tid], p + 1)) s_ok = 0;
      }
      __syncthreads();
      if (tid == 0) store_u32_llc((unsigned*)&ctr[F_GO], p + 1);
    }
    if (tid == 0) {
      if (!spin_ge(&ctr[F_GO], p + 1)) s_ok = 0;
    }
    __syncthreads();
    if (!s_ok) break;
  }
}

// ======================= host launch =======================================

extern "C" void kernel_launch(void* const* d_in, const int* in_sizes, int n_in,
                              void* d_out, int out_size, void* d_ws, size_t ws_size,
                              hipStream_t stream) {
  const int*   ib   = (const int*)d_in[0];
  const int*   lens = (const int*)d_in[1];
  const float* emb  = (const float*)d_in[2];
  const float* W0   = (const float*)d_in[3];
  const float* b0   = (const float*)d_in[4];
  const float* W1   = (const float*)d_in[5];
  const float* b1   = (const float*)d_in[6];
  (void)in_sizes; (void)n_in; (void)out_size; (void)ws_size;

  char* ws = (char*)d_ws;
  size_t off = 0;
  auto alloc = [&](size_t bytes) { char* q = ws + off; off += (bytes + 255) & ~(size_t)255; return q; };

  int*            ctr   = (int*)alloc(8192);
  unsigned short* hg0hi = (unsigned short*)alloc((size_t)3 * HP * 2);
  unsigned short* hg0lo = (unsigned short*)alloc((size_t)3 * HP * 2);
  unsigned short* hg1hi = (unsigned short*)alloc((size_t)3 * HP * 2);
  unsigned short* hg1lo = (unsigned short*)alloc((size_t)3 * HP * 2);
  const size_t zero_bytes = off;          // ctr + h planes
  unsigned short* embHi = (unsigned short*)alloc(128 * 256 * 2);
  unsigned short* embLo = (unsigned short*)alloc(128 * 256 * 2);
  int*            perm  = (int*)alloc(4096);
  int*            lenS  = perm + 128;
  int*            ncnt  = perm + 256;
  unsigned short* rep   = (unsigned short*)alloc((size_t)8 * 4 * HP * 2);
  uint4*          Whi0  = (uint4*)alloc((size_t)NBLK * KT0B * 64 * 16);
  uint4*          Wlo0  = (uint4*)alloc((size_t)NBLK * KT0B * 64 * 16);
  uint4*          Whi1  = (uint4*)alloc((size_t)NBLK * KT1B * 64 * 16);
  uint4*          Wlo1  = (uint4*)alloc((size_t)NBLK * KT1B * 64 * 16);

  hipMemsetAsync(d_ws, 0, zero_bytes, stream);
  prep_sort<<<1, 512, 0, stream>>>(lens, perm, lenS, ncnt);
  prep_emb<<<128, 256, 0, stream>>>(emb, embHi, embLo);
  prep_wslab<<<(NBLK * KT0B * 64) / 256, 256, 0, stream>>>(W0, Whi0, Wlo0, KT0B);
  prep_wslab<<<(NBLK * KT1B * 64) / 256, 256, 0, stream>>>(W1, Whi1, Wlo1, KT1B);
  lstm_persist<<<NBLK, THREADS, 0, stream>>>(
      ib, b0, b1, Whi0, Wlo0, Whi1, Wlo1, embHi, embLo,
      perm, lenS, ncnt, hg0hi, hg0lo, hg1hi, hg1lo, rep, ctr, (float*)d_out);
}